// Round 1
// baseline (1656.800 us; speedup 1.0000x reference)
//
#include <hip/hip_runtime.h>

#define BB 16
#define NN 4096
#define NT 1024
#define EPT 4
#define MAXP 300
#define IOU_THRESH 0.7f
#define SCORE_THRESH 0.5f

__global__ __launch_bounds__(NT) void nms_kernel(const float* __restrict__ proposals,
                                                 const float* __restrict__ cls,
                                                 float* __restrict__ out) {
    __shared__ unsigned long long skeys[NN];   // 32 KB
    __shared__ unsigned char ssup[NN];         // 4 KB
    __shared__ unsigned int ssel[MAXP];
    __shared__ unsigned int swsum[NT / 64];
    __shared__ unsigned int s_nvalid;
    __shared__ unsigned int s_nk;

    const int b = blockIdx.x;
    const int tid = threadIdx.x;
    const float* Pb = proposals + (size_t)b * NN * 4;
    const float* Cb = cls + (size_t)b * NN * 2;

    if (tid == 0) s_nvalid = 0;
    __syncthreads();

    // ---- build sort keys: (monotone score bits << 32) | ~index ----
    unsigned lv = 0;
    for (int i = tid; i < NN; i += NT) {
        float sc = Cb[i * 2 + 1];
        bool valid = sc > SCORE_THRESH;
        unsigned mb = valid ? (__float_as_uint(sc) | 0x80000000u) : 0u;
        skeys[i] = ((unsigned long long)mb << 32) | (unsigned)(~i);
        lv += valid ? 1u : 0u;
    }
    for (int off = 32; off > 0; off >>= 1) lv += __shfl_down(lv, off, 64);
    if ((tid & 63) == 0) atomicAdd(&s_nvalid, lv);

    // ---- bitonic sort, descending ----
    for (unsigned k = 2; k <= NN; k <<= 1) {
        for (unsigned j = k >> 1; j > 0; j >>= 1) {
            __syncthreads();
            for (unsigned i = tid; i < NN; i += NT) {
                unsigned ixj = i ^ j;
                if (ixj > i) {
                    unsigned long long a = skeys[i], c = skeys[ixj];
                    bool up = ((i & k) == 0);
                    if ((a < c) == up) { skeys[i] = c; skeys[ixj] = a; }
                }
            }
        }
    }
    __syncthreads();

    const unsigned n_valid = s_nvalid;

    // ---- per-thread sorted boxes (contiguous mapping j = tid*4+c) ----
    unsigned ordj[EPT];
    float bx1[EPT], by1[EPT], bx2[EPT], by2[EPT], bar[EPT];
    for (int c = 0; c < EPT; ++c) {
        int j = tid * EPT + c;
        unsigned oi = ~(unsigned)skeys[j];   // low 32 bits hold ~index
        ordj[c] = oi;
        const float* P = Pb + (size_t)oi * 4;
        float x1 = P[0], y1 = P[1], x2 = P[2], y2 = P[3];
        bx1[c] = x1; by1[c] = y1; bx2[c] = x2; by2[c] = y2;
        bar[c] = __fmul_rn(__fsub_rn(x2, x1), __fsub_rn(y2, y1));
        ssup[j] = (j < (int)n_valid) ? 0 : 1;
    }
    __syncthreads();

    // ---- serial greedy NMS ----
    for (unsigned i = 0; i < n_valid; ++i) {
        if (ssup[i]) continue;               // uniform: no writes since last barrier
        unsigned oi = ~(unsigned)skeys[i];
        const float* Pi = Pb + (size_t)oi * 4;
        float ix1 = Pi[0], iy1 = Pi[1], ix2 = Pi[2], iy2 = Pi[3];
        float ia = __fmul_rn(__fsub_rn(ix2, ix1), __fsub_rn(iy2, iy1));
        for (int c = 0; c < EPT; ++c) {
            int j = tid * EPT + c;
            if (j > (int)i) {
                float xx1 = fmaxf(ix1, bx1[c]);
                float yy1 = fmaxf(iy1, by1[c]);
                float xx2 = fminf(ix2, bx2[c]);
                float yy2 = fminf(iy2, by2[c]);
                float iw = fmaxf(__fsub_rn(xx2, xx1), 0.0f);
                float ih = fmaxf(__fsub_rn(yy2, yy1), 0.0f);
                float inter = __fmul_rn(iw, ih);
                float uni = __fsub_rn(__fadd_rn(ia, bar[c]), inter);
                float iou = __fdiv_rn(inter, uni);
                if (iou >= IOU_THRESH) ssup[j] = 1;
            }
        }
        __syncthreads();
    }
    __syncthreads();

    // ---- prefix sum of keep flags -> ranks ----
    unsigned kflag[EPT];
    unsigned lc = 0;
    for (int c = 0; c < EPT; ++c) {
        int j = tid * EPT + c;
        kflag[c] = ssup[j] ? 0u : 1u;
        lc += kflag[c];
    }
    unsigned lane = tid & 63, wid = tid >> 6;
    unsigned inc = lc;
    for (int off = 1; off < 64; off <<= 1) {
        unsigned o = __shfl_up(inc, off, 64);
        if (lane >= (unsigned)off) inc += o;
    }
    if (lane == 63) swsum[wid] = inc;
    __syncthreads();
    if (tid == 0) {
        unsigned run = 0;
        for (int w = 0; w < NT / 64; ++w) { unsigned t = swsum[w]; swsum[w] = run; run += t; }
        s_nk = run;
    }
    __syncthreads();
    unsigned base = swsum[wid] + (inc - lc);
    for (int c = 0; c < EPT; ++c) {
        if (kflag[c]) {
            if (base < MAXP) ssel[base] = ordj[c];
            ++base;
        }
    }
    const unsigned nk = s_nk;
    __syncthreads();

    // ---- padding (matches reference clip semantics) ----
    if (tid < MAXP) {
        if (nk == 0) {
            ssel[tid] = ~(unsigned)skeys[NN - 1];
        } else if (tid >= nk) {
            ssel[tid] = ssel[nk - 1];
        }
    }
    __syncthreads();

    // ---- gather outputs ----
    if (tid < MAXP) {
        unsigned si = ssel[tid];
        const float* P = Pb + (size_t)si * 4;
        float* ob = out + ((size_t)b * MAXP + tid) * 4;
        ob[0] = P[0]; ob[1] = P[1]; ob[2] = P[2]; ob[3] = P[3];
        out[(size_t)BB * MAXP * 4 + (size_t)b * MAXP + tid] = Cb[si * 2 + 1];
    }
}

extern "C" void kernel_launch(void* const* d_in, const int* in_sizes, int n_in,
                              void* d_out, int out_size, void* d_ws, size_t ws_size,
                              hipStream_t stream) {
    const float* proposals = (const float*)d_in[0];
    const float* cls = (const float*)d_in[1];
    float* out = (float*)d_out;
    nms_kernel<<<BB, NT, 0, stream>>>(proposals, cls, out);
}

// Round 2
// 1322.999 us; speedup vs baseline: 1.2523x; 1.2523x over previous
//
#include <hip/hip_runtime.h>

#define BB 16
#define NN 4096
#define NT 1024
#define EPT 4
#define MAXP 300
#define IOU_THRESH 0.7f
#define SCORE_THRESH 0.5f
#define CH 64
#define TPC (CH / EPT)   // threads owning one chunk = 16

__global__ __launch_bounds__(NT) void nms_kernel(const float* __restrict__ proposals,
                                                 const float* __restrict__ cls,
                                                 float* __restrict__ out) {
    __shared__ unsigned long long skeys[NN];   // 32 KB
    __shared__ unsigned char ssup[NN];         // 4 KB
    __shared__ float cbx1[2][CH], cby1[2][CH], cbx2[2][CH], cby2[2][CH], cbar[2][CH];
    __shared__ unsigned long long skept[2];
    __shared__ unsigned int ssel[MAXP];
    __shared__ unsigned int swsum[NT / 64];
    __shared__ unsigned int s_nvalid;
    __shared__ unsigned int s_nk;

    const int b = blockIdx.x;
    const int tid = threadIdx.x;
    const float* Pb = proposals + (size_t)b * NN * 4;
    const float* Cb = cls + (size_t)b * NN * 2;

    if (tid == 0) s_nvalid = 0;
    __syncthreads();

    // ---- build sort keys: (monotone score bits << 32) | ~index ----
    unsigned lv = 0;
    for (int i = tid; i < NN; i += NT) {
        float sc = Cb[i * 2 + 1];
        bool valid = sc > SCORE_THRESH;
        unsigned mb = valid ? (__float_as_uint(sc) | 0x80000000u) : 0u;
        skeys[i] = ((unsigned long long)mb << 32) | (unsigned)(~i);
        lv += valid ? 1u : 0u;
    }
    for (int off = 32; off > 0; off >>= 1) lv += __shfl_down(lv, off, 64);
    if ((tid & 63) == 0) atomicAdd(&s_nvalid, lv);

    // ---- bitonic sort, descending ----
    for (unsigned k = 2; k <= NN; k <<= 1) {
        for (unsigned j = k >> 1; j > 0; j >>= 1) {
            __syncthreads();
            for (unsigned i = tid; i < NN; i += NT) {
                unsigned ixj = i ^ j;
                if (ixj > i) {
                    unsigned long long a = skeys[i], c = skeys[ixj];
                    bool up = ((i & k) == 0);
                    if ((a < c) == up) { skeys[i] = c; skeys[ixj] = a; }
                }
            }
        }
    }
    __syncthreads();

    const unsigned n_valid = s_nvalid;

    // ---- per-thread sorted boxes (contiguous mapping j = tid*4+c2) ----
    unsigned ordj[EPT];
    float bx1[EPT], by1[EPT], bx2[EPT], by2[EPT], bar[EPT];
    int rflag[EPT];
    for (int c2 = 0; c2 < EPT; ++c2) {
        int j = tid * EPT + c2;
        unsigned oi = ~(unsigned)skeys[j];
        ordj[c2] = oi;
        const float* P = Pb + (size_t)oi * 4;
        float x1 = P[0], y1 = P[1], x2 = P[2], y2 = P[3];
        bx1[c2] = x1; by1[c2] = y1; bx2[c2] = x2; by2[c2] = y2;
        bar[c2] = __fmul_rn(__fsub_rn(x2, x1), __fsub_rn(y2, y1));
        int sup = (j < (int)n_valid) ? 0 : 1;
        rflag[c2] = sup;
        ssup[j] = (unsigned char)sup;
    }

    // ---- chunked greedy NMS ----
    const unsigned nch = (n_valid + CH - 1) / CH;
    for (unsigned c = 0; c < nch; ++c) {
        const int p = (int)(c & 1);
        // stage chunk c's boxes (owner threads have them in registers)
        if (tid >= (int)(TPC * c) && tid < (int)(TPC * (c + 1))) {
            int base = (tid - TPC * c) * EPT;
            #pragma unroll
            for (int c2 = 0; c2 < EPT; ++c2) {
                int l = base + c2;
                cbx1[p][l] = bx1[c2]; cby1[p][l] = by1[c2];
                cbx2[p][l] = bx2[c2]; cby2[p][l] = by2[c2];
                cbar[p][l] = bar[c2];
            }
        }
        __syncthreads();   // staging + prior ssup writes visible

        // wave 0: intra-chunk resolve (lockstep, no barriers)
        if (tid < CH) {
            const int l = tid;
            const int j = (int)(c * CH) + l;
            float x1 = cbx1[p][l], y1 = cby1[p][l], x2 = cbx2[p][l], y2 = cby2[p][l];
            float ar = cbar[p][l];
            int supl = ssup[j];
            unsigned long long row = 0ULL;
            for (int m = l + 1; m < CH; ++m) {
                float xx1 = fmaxf(x1, cbx1[p][m]);
                float yy1 = fmaxf(y1, cby1[p][m]);
                float xx2 = fminf(x2, cbx2[p][m]);
                float yy2 = fminf(y2, cby2[p][m]);
                float iw = fmaxf(__fsub_rn(xx2, xx1), 0.0f);
                float ih = fmaxf(__fsub_rn(yy2, yy1), 0.0f);
                float inter = __fmul_rn(iw, ih);
                float uni = __fsub_rn(__fadd_rn(ar, cbar[p][m]), inter);
                float iou = __fdiv_rn(inter, uni);
                if (iou >= IOU_THRESH) row |= (1ULL << m);
            }
            unsigned long long S = __ballot(supl != 0);
            for (int i = 0; i < CH; ++i) {
                unsigned long long ri = __shfl(row, i, 64);
                if (!((S >> i) & 1ULL)) S |= ri;
            }
            ssup[j] = (unsigned char)((S >> l) & 1ULL);
            if (l == 0) skept[p] = ~S;
        }
        __syncthreads();   // resolve results visible

        // cross-apply: chunk's kept boxes suppress later boxes
        const int myFirst = tid * EPT;
        if (myFirst >= (int)(CH * (c + 1)) &&
            !(rflag[0] & rflag[1] & rflag[2] & rflag[3])) {
            unsigned long long K = skept[p];
            while (K) {
                int m = __builtin_ctzll(K);
                K &= K - 1;
                float mx1 = cbx1[p][m], my1 = cby1[p][m];
                float mx2 = cbx2[p][m], my2 = cby2[p][m];
                float ma = cbar[p][m];
                #pragma unroll
                for (int c2 = 0; c2 < EPT; ++c2) {
                    if (!rflag[c2]) {
                        float xx1 = fmaxf(mx1, bx1[c2]);
                        float yy1 = fmaxf(my1, by1[c2]);
                        float xx2 = fminf(mx2, bx2[c2]);
                        float yy2 = fminf(my2, by2[c2]);
                        float iw = fmaxf(__fsub_rn(xx2, xx1), 0.0f);
                        float ih = fmaxf(__fsub_rn(yy2, yy1), 0.0f);
                        float inter = __fmul_rn(iw, ih);
                        float uni = __fsub_rn(__fadd_rn(ma, bar[c2]), inter);
                        float iou = __fdiv_rn(inter, uni);
                        if (iou >= IOU_THRESH) {
                            rflag[c2] = 1;
                            ssup[myFirst + c2] = 1;
                        }
                    }
                }
            }
        }
        // next iteration stages the other buffer; no barrier needed here
    }
    __syncthreads();

    // ---- prefix sum of keep flags -> ranks ----
    unsigned kflag[EPT];
    unsigned lc = 0;
    for (int c2 = 0; c2 < EPT; ++c2) {
        int j = tid * EPT + c2;
        kflag[c2] = ssup[j] ? 0u : 1u;
        lc += kflag[c2];
    }
    unsigned lane = tid & 63, wid = tid >> 6;
    unsigned inc = lc;
    for (int off = 1; off < 64; off <<= 1) {
        unsigned o = __shfl_up(inc, off, 64);
        if (lane >= (unsigned)off) inc += o;
    }
    if (lane == 63) swsum[wid] = inc;
    __syncthreads();
    if (tid == 0) {
        unsigned run = 0;
        for (int w = 0; w < NT / 64; ++w) { unsigned t = swsum[w]; swsum[w] = run; run += t; }
        s_nk = run;
    }
    __syncthreads();
    unsigned base = swsum[wid] + (inc - lc);
    for (int c2 = 0; c2 < EPT; ++c2) {
        if (kflag[c2]) {
            if (base < MAXP) ssel[base] = ordj[c2];
            ++base;
        }
    }
    const unsigned nk_pre = s_nk;
    __syncthreads();

    // ---- padding (matches reference clip semantics) ----
    if (tid < MAXP) {
        if (nk_pre == 0) {
            ssel[tid] = ~(unsigned)skeys[NN - 1];
        } else if (tid >= nk_pre) {
            ssel[tid] = ssel[nk_pre - 1];
        }
    }
    __syncthreads();

    // ---- gather outputs ----
    if (tid < MAXP) {
        unsigned si = ssel[tid];
        const float* P = Pb + (size_t)si * 4;
        float* ob = out + ((size_t)b * MAXP + tid) * 4;
        ob[0] = P[0]; ob[1] = P[1]; ob[2] = P[2]; ob[3] = P[3];
        out[(size_t)BB * MAXP * 4 + (size_t)b * MAXP + tid] = Cb[si * 2 + 1];
    }
}

extern "C" void kernel_launch(void* const* d_in, const int* in_sizes, int n_in,
                              void* d_out, int out_size, void* d_ws, size_t ws_size,
                              hipStream_t stream) {
    const float* proposals = (const float*)d_in[0];
    const float* cls = (const float*)d_in[1];
    float* out = (float*)d_out;
    nms_kernel<<<BB, NT, 0, stream>>>(proposals, cls, out);
}

// Round 3
// 350.213 us; speedup vs baseline: 4.7308x; 3.7777x over previous
//
#include <hip/hip_runtime.h>

typedef unsigned long long ull;

#define BB 16
#define NN 4096
#define NT 1024
#define EPT 4
#define MAXP 300
#define IOU_THRESH 0.7f
#define SCORE_THRESH 0.5f
#define WPR 64                 // 64-bit words per mask row (NN/64)
#define BPI 32                 // mask-kernel blocks per image
#define BT 256                 // mask-kernel threads per block
#define ROWS_PER_BLOCK (NN / BPI)              // 128
#define ROWS_PER_WAVE (ROWS_PER_BLOCK / (BT/64))  // 32

// ---------------- Kernel A: key build + bitonic sort + SoA scatter ----------------
__global__ __launch_bounds__(NT) void sort_kernel(const float* __restrict__ proposals,
                                                  const float* __restrict__ cls,
                                                  float* __restrict__ wx1, float* __restrict__ wy1,
                                                  float* __restrict__ wx2, float* __restrict__ wy2,
                                                  unsigned* __restrict__ sord,
                                                  unsigned* __restrict__ wnv) {
    __shared__ ull skeys[NN];
    __shared__ unsigned s_nvalid;
    const int b = blockIdx.x, tid = threadIdx.x;
    const float* Cb = cls + (size_t)b * NN * 2;
    const float4* Pb4 = (const float4*)(proposals + (size_t)b * NN * 4);

    if (tid == 0) s_nvalid = 0;
    __syncthreads();

    unsigned lv = 0;
    for (int i = tid; i < NN; i += NT) {
        float sc = Cb[i * 2 + 1];
        bool valid = sc > SCORE_THRESH;
        unsigned mb = valid ? (__float_as_uint(sc) | 0x80000000u) : 0u;
        skeys[i] = ((ull)mb << 32) | (unsigned)(~i);
        lv += valid ? 1u : 0u;
    }
    for (int off = 32; off > 0; off >>= 1) lv += __shfl_down(lv, off, 64);
    if ((tid & 63) == 0) atomicAdd(&s_nvalid, lv);

    // bitonic sort, descending; enumerate only active pairs (2048)
    for (unsigned k = 2; k <= NN; k <<= 1) {
        for (unsigned j = k >> 1; j > 0; j >>= 1) {
            __syncthreads();
            for (unsigned p = tid; p < NN / 2; p += NT) {
                unsigned low = p & (j - 1);
                unsigned i = ((p ^ low) << 1) | low;   // bit log2(j) clear
                unsigned ixj = i | j;
                ull a = skeys[i], c = skeys[ixj];
                if ((a < c) == ((i & k) == 0)) { skeys[i] = c; skeys[ixj] = a; }
            }
        }
    }
    __syncthreads();

    const size_t base = (size_t)b * NN;
    for (int c = 0; c < EPT; ++c) {
        int j = tid * EPT + c;
        unsigned oi = ~(unsigned)skeys[j];
        sord[base + j] = oi;
        float4 v = Pb4[oi];
        wx1[base + j] = v.x; wy1[base + j] = v.y;
        wx2[base + j] = v.z; wy2[base + j] = v.w;
    }
    if (tid == 0) wnv[b] = s_nvalid;
}

// ---------------- Kernel B: suppression bit-matrix (whole GPU) ----------------
__global__ __launch_bounds__(BT) void mask_kernel(const float* __restrict__ wx1, const float* __restrict__ wy1,
                                                  const float* __restrict__ wx2, const float* __restrict__ wy2,
                                                  const unsigned* __restrict__ wnv,
                                                  ull* __restrict__ mask) {
    __shared__ float sx1[NN], sy1[NN], sx2[NN], sy2[NN];   // 64 KB
    const int img = blockIdx.y;
    const unsigned nv = wnv[img];
    const unsigned rowbase = blockIdx.x * ROWS_PER_BLOCK;
    if (rowbase >= nv) return;
    const int tid = threadIdx.x;
    const size_t base = (size_t)img * NN;

    for (int idx = tid; idx < NN; idx += BT) {
        sx1[idx] = wx1[base + idx];
        sy1[idx] = wy1[base + idx];
        sx2[idx] = wx2[base + idx];
        sy2[idx] = wy2[base + idx];
    }
    __syncthreads();

    const unsigned lane = tid & 63, wave = tid >> 6;
    const unsigned wlast = (nv - 1) >> 6;
    ull* mimg = mask + base * WPR;

    for (unsigned rr = 0; rr < ROWS_PER_WAVE; ++rr) {
        unsigned i = rowbase + wave * ROWS_PER_WAVE + rr;
        if (i >= nv) break;
        float ix1 = sx1[i], iy1 = sy1[i], ix2 = sx2[i], iy2 = sy2[i];
        float ia = __fmul_rn(__fsub_rn(ix2, ix1), __fsub_rn(iy2, iy1));
        unsigned w0 = i >> 6;
        ull my = 0;
        for (unsigned w = w0; w <= wlast; ++w) {
            unsigned jj = (w << 6) | lane;
            float x1j = sx1[jj], y1j = sy1[jj], x2j = sx2[jj], y2j = sy2[jj];
            float aj = __fmul_rn(__fsub_rn(x2j, x1j), __fsub_rn(y2j, y1j));
            float xx1 = fmaxf(ix1, x1j);
            float yy1 = fmaxf(iy1, y1j);
            float xx2 = fminf(ix2, x2j);
            float yy2 = fminf(iy2, y2j);
            float iw = fmaxf(__fsub_rn(xx2, xx1), 0.0f);
            float ih = fmaxf(__fsub_rn(yy2, yy1), 0.0f);
            float inter = __fmul_rn(iw, ih);
            float uni = __fsub_rn(__fadd_rn(ia, aj), inter);
            float iou = __fdiv_rn(inter, uni);
            bool pred = (jj > i) && (iou >= IOU_THRESH);
            ull bal = __ballot(pred);
            if (lane == w) my = bal;
        }
        mimg[(size_t)i * WPR + lane] = my;   // coalesced 512 B row store
    }
}

// ---------------- Kernel C: serial OR-scan + compact + output ----------------
__global__ __launch_bounds__(NT) void scan_out_kernel(const float* __restrict__ proposals,
                                                      const float* __restrict__ cls,
                                                      const unsigned* __restrict__ sord,
                                                      const unsigned* __restrict__ wnv,
                                                      const ull* __restrict__ mask,
                                                      float* __restrict__ out) {
    __shared__ ull ssw[WPR];
    __shared__ unsigned ssel[MAXP];
    __shared__ unsigned swsum[NT / 64];
    __shared__ unsigned s_nk;
    const int b = blockIdx.x, tid = threadIdx.x;
    const unsigned nv = wnv[b];
    const size_t base = (size_t)b * NN;
    const float* Pb = proposals + base * 4;
    const float* Cb = cls + base * 2;

    if (tid < 64) {
        const int lane = tid;
        unsigned lb = (unsigned)lane << 6;
        ull sup;
        if (lb >= nv) sup = ~0ULL;
        else if (lb + 64 <= nv) sup = 0ULL;
        else sup = (~0ULL) << (nv - lb);

        if (nv > 0) {
            const ull* mrow = mask + base * WPR;
            ull buf[8];
            unsigned ng = (nv + 7) >> 3;
            #pragma unroll
            for (int k2 = 0; k2 < 8; ++k2)
                buf[k2] = mrow[(size_t)k2 * WPR + lane];
            for (unsigned g = 0; g < ng; ++g) {
                ull cur[8];
                #pragma unroll
                for (int k2 = 0; k2 < 8; ++k2) cur[k2] = buf[k2];
                unsigned nb = (g + 1) * 8;
                #pragma unroll
                for (int k2 = 0; k2 < 8; ++k2) {
                    unsigned r2 = nb + (unsigned)k2;
                    if (r2 >= NN) r2 = 0;
                    buf[k2] = mrow[(size_t)r2 * WPR + lane];
                }
                #pragma unroll
                for (int k2 = 0; k2 < 8; ++k2) {
                    unsigned i = g * 8 + (unsigned)k2;
                    bool keptbit = ((unsigned)lane == (i >> 6)) && (i < nv) &&
                                   (((sup >> (i & 63)) & 1ULL) == 0ULL);
                    ull km = __ballot(keptbit);
                    if (km) sup |= cur[k2];
                }
            }
        }
        ssw[lane] = sup;
    }
    __syncthreads();

    // ---- prefix sum of keep flags -> ranks ----
    unsigned ordj[EPT], kflag[EPT];
    unsigned lc = 0;
    for (int c = 0; c < EPT; ++c) {
        int j = tid * EPT + c;
        ordj[c] = sord[base + j];
        unsigned bit = (unsigned)((ssw[j >> 6] >> (j & 63)) & 1ULL);
        kflag[c] = bit ^ 1u;
        lc += kflag[c];
    }
    unsigned lane = tid & 63, wid = tid >> 6;
    unsigned inc = lc;
    for (int off = 1; off < 64; off <<= 1) {
        unsigned o = __shfl_up(inc, off, 64);
        if (lane >= (unsigned)off) inc += o;
    }
    if (lane == 63) swsum[wid] = inc;
    __syncthreads();
    if (tid == 0) {
        unsigned run = 0;
        for (int w = 0; w < NT / 64; ++w) { unsigned t = swsum[w]; swsum[w] = run; run += t; }
        s_nk = run;
    }
    __syncthreads();
    unsigned pos = swsum[wid] + (inc - lc);
    for (int c = 0; c < EPT; ++c) {
        if (kflag[c]) {
            if (pos < MAXP) ssel[pos] = ordj[c];
            ++pos;
        }
    }
    const unsigned nk = s_nk;
    __syncthreads();

    if (tid < MAXP) {
        if (nk == 0) {
            ssel[tid] = sord[base + NN - 1];
        } else if (tid >= nk) {
            ssel[tid] = ssel[nk - 1];
        }
    }
    __syncthreads();

    if (tid < MAXP) {
        unsigned si = ssel[tid];
        const float* P = Pb + (size_t)si * 4;
        float* ob = out + ((size_t)b * MAXP + tid) * 4;
        ob[0] = P[0]; ob[1] = P[1]; ob[2] = P[2]; ob[3] = P[3];
        out[(size_t)BB * MAXP * 4 + (size_t)b * MAXP + tid] = Cb[si * 2 + 1];
    }
}

// ---------------- Fallback (round-2 monolithic, used if ws too small) ----------------
#define CH 64
#define TPC (CH / EPT)
__global__ __launch_bounds__(NT) void nms_fallback(const float* __restrict__ proposals,
                                                   const float* __restrict__ cls,
                                                   float* __restrict__ out) {
    __shared__ unsigned long long skeys[NN];
    __shared__ unsigned char ssup[NN];
    __shared__ float cbx1[2][CH], cby1[2][CH], cbx2[2][CH], cby2[2][CH], cbar[2][CH];
    __shared__ unsigned long long skept[2];
    __shared__ unsigned int ssel[MAXP];
    __shared__ unsigned int swsum[NT / 64];
    __shared__ unsigned int s_nvalid;
    __shared__ unsigned int s_nk;

    const int b = blockIdx.x;
    const int tid = threadIdx.x;
    const float* Pb = proposals + (size_t)b * NN * 4;
    const float* Cb = cls + (size_t)b * NN * 2;

    if (tid == 0) s_nvalid = 0;
    __syncthreads();

    unsigned lv = 0;
    for (int i = tid; i < NN; i += NT) {
        float sc = Cb[i * 2 + 1];
        bool valid = sc > SCORE_THRESH;
        unsigned mb = valid ? (__float_as_uint(sc) | 0x80000000u) : 0u;
        skeys[i] = ((unsigned long long)mb << 32) | (unsigned)(~i);
        lv += valid ? 1u : 0u;
    }
    for (int off = 32; off > 0; off >>= 1) lv += __shfl_down(lv, off, 64);
    if ((tid & 63) == 0) atomicAdd(&s_nvalid, lv);

    for (unsigned k = 2; k <= NN; k <<= 1) {
        for (unsigned j = k >> 1; j > 0; j >>= 1) {
            __syncthreads();
            for (unsigned i = tid; i < NN; i += NT) {
                unsigned ixj = i ^ j;
                if (ixj > i) {
                    unsigned long long a = skeys[i], c = skeys[ixj];
                    bool up = ((i & k) == 0);
                    if ((a < c) == up) { skeys[i] = c; skeys[ixj] = a; }
                }
            }
        }
    }
    __syncthreads();

    const unsigned n_valid = s_nvalid;

    unsigned ordj[EPT];
    float bx1[EPT], by1[EPT], bx2[EPT], by2[EPT], bar[EPT];
    int rflag[EPT];
    for (int c2 = 0; c2 < EPT; ++c2) {
        int j = tid * EPT + c2;
        unsigned oi = ~(unsigned)skeys[j];
        ordj[c2] = oi;
        const float* P = Pb + (size_t)oi * 4;
        float x1 = P[0], y1 = P[1], x2 = P[2], y2 = P[3];
        bx1[c2] = x1; by1[c2] = y1; bx2[c2] = x2; by2[c2] = y2;
        bar[c2] = __fmul_rn(__fsub_rn(x2, x1), __fsub_rn(y2, y1));
        int sup = (j < (int)n_valid) ? 0 : 1;
        rflag[c2] = sup;
        ssup[j] = (unsigned char)sup;
    }

    const unsigned nch = (n_valid + CH - 1) / CH;
    for (unsigned c = 0; c < nch; ++c) {
        const int p = (int)(c & 1);
        if (tid >= (int)(TPC * c) && tid < (int)(TPC * (c + 1))) {
            int bse = (tid - TPC * c) * EPT;
            #pragma unroll
            for (int c2 = 0; c2 < EPT; ++c2) {
                int l = bse + c2;
                cbx1[p][l] = bx1[c2]; cby1[p][l] = by1[c2];
                cbx2[p][l] = bx2[c2]; cby2[p][l] = by2[c2];
                cbar[p][l] = bar[c2];
            }
        }
        __syncthreads();

        if (tid < CH) {
            const int l = tid;
            const int j = (int)(c * CH) + l;
            float x1 = cbx1[p][l], y1 = cby1[p][l], x2 = cbx2[p][l], y2 = cby2[p][l];
            float ar = cbar[p][l];
            int supl = ssup[j];
            unsigned long long row = 0ULL;
            for (int m = l + 1; m < CH; ++m) {
                float xx1 = fmaxf(x1, cbx1[p][m]);
                float yy1 = fmaxf(y1, cby1[p][m]);
                float xx2 = fminf(x2, cbx2[p][m]);
                float yy2 = fminf(y2, cby2[p][m]);
                float iw = fmaxf(__fsub_rn(xx2, xx1), 0.0f);
                float ih = fmaxf(__fsub_rn(yy2, yy1), 0.0f);
                float inter = __fmul_rn(iw, ih);
                float uni = __fsub_rn(__fadd_rn(ar, cbar[p][m]), inter);
                float iou = __fdiv_rn(inter, uni);
                if (iou >= IOU_THRESH) row |= (1ULL << m);
            }
            unsigned long long S = __ballot(supl != 0);
            for (int i = 0; i < CH; ++i) {
                unsigned long long ri = __shfl(row, i, 64);
                if (!((S >> i) & 1ULL)) S |= ri;
            }
            ssup[j] = (unsigned char)((S >> l) & 1ULL);
            if (l == 0) skept[p] = ~S;
        }
        __syncthreads();

        const int myFirst = tid * EPT;
        if (myFirst >= (int)(CH * (c + 1)) &&
            !(rflag[0] & rflag[1] & rflag[2] & rflag[3])) {
            unsigned long long K = skept[p];
            while (K) {
                int m = __builtin_ctzll(K);
                K &= K - 1;
                float mx1 = cbx1[p][m], my1 = cby1[p][m];
                float mx2 = cbx2[p][m], my2 = cby2[p][m];
                float ma = cbar[p][m];
                #pragma unroll
                for (int c2 = 0; c2 < EPT; ++c2) {
                    if (!rflag[c2]) {
                        float xx1 = fmaxf(mx1, bx1[c2]);
                        float yy1 = fmaxf(my1, by1[c2]);
                        float xx2 = fminf(mx2, bx2[c2]);
                        float yy2 = fminf(my2, by2[c2]);
                        float iw = fmaxf(__fsub_rn(xx2, xx1), 0.0f);
                        float ih = fmaxf(__fsub_rn(yy2, yy1), 0.0f);
                        float inter = __fmul_rn(iw, ih);
                        float uni = __fsub_rn(__fadd_rn(ma, bar[c2]), inter);
                        float iou = __fdiv_rn(inter, uni);
                        if (iou >= IOU_THRESH) {
                            rflag[c2] = 1;
                            ssup[myFirst + c2] = 1;
                        }
                    }
                }
            }
        }
    }
    __syncthreads();

    unsigned kflag[EPT];
    unsigned lc = 0;
    for (int c2 = 0; c2 < EPT; ++c2) {
        int j = tid * EPT + c2;
        kflag[c2] = ssup[j] ? 0u : 1u;
        lc += kflag[c2];
    }
    unsigned lane = tid & 63, wid = tid >> 6;
    unsigned inc = lc;
    for (int off = 1; off < 64; off <<= 1) {
        unsigned o = __shfl_up(inc, off, 64);
        if (lane >= (unsigned)off) inc += o;
    }
    if (lane == 63) swsum[wid] = inc;
    __syncthreads();
    if (tid == 0) {
        unsigned run = 0;
        for (int w = 0; w < NT / 64; ++w) { unsigned t = swsum[w]; swsum[w] = run; run += t; }
        s_nk = run;
    }
    __syncthreads();
    unsigned bse = swsum[wid] + (inc - lc);
    for (int c2 = 0; c2 < EPT; ++c2) {
        if (kflag[c2]) {
            if (bse < MAXP) ssel[bse] = ordj[c2];
            ++bse;
        }
    }
    const unsigned nk_pre = s_nk;
    __syncthreads();

    if (tid < MAXP) {
        if (nk_pre == 0) {
            ssel[tid] = ~(unsigned)skeys[NN - 1];
        } else if (tid >= nk_pre) {
            ssel[tid] = ssel[nk_pre - 1];
        }
    }
    __syncthreads();

    if (tid < MAXP) {
        unsigned si = ssel[tid];
        const float* P = Pb + (size_t)si * 4;
        float* ob = out + ((size_t)b * MAXP + tid) * 4;
        ob[0] = P[0]; ob[1] = P[1]; ob[2] = P[2]; ob[3] = P[3];
        out[(size_t)BB * MAXP * 4 + (size_t)b * MAXP + tid] = Cb[si * 2 + 1];
    }
}

extern "C" void kernel_launch(void* const* d_in, const int* in_sizes, int n_in,
                              void* d_out, int out_size, void* d_ws, size_t ws_size,
                              hipStream_t stream) {
    const float* proposals = (const float*)d_in[0];
    const float* cls = (const float*)d_in[1];
    float* out = (float*)d_out;

    const size_t MASK_BYTES = (size_t)BB * NN * WPR * sizeof(ull);   // 32 MB
    const size_t SOA = (size_t)BB * NN;
    const size_t need = MASK_BYTES + SOA * 4 * sizeof(float) + SOA * sizeof(unsigned) + 256;

    if (ws_size < need) {
        nms_fallback<<<BB, NT, 0, stream>>>(proposals, cls, out);
        return;
    }

    ull* mask = (ull*)d_ws;
    float* wx1 = (float*)((char*)d_ws + MASK_BYTES);
    float* wy1 = wx1 + SOA;
    float* wx2 = wy1 + SOA;
    float* wy2 = wx2 + SOA;
    unsigned* sord = (unsigned*)(wy2 + SOA);
    unsigned* wnv = sord + SOA;

    sort_kernel<<<BB, NT, 0, stream>>>(proposals, cls, wx1, wy1, wx2, wy2, sord, wnv);
    mask_kernel<<<dim3(BPI, BB), BT, 0, stream>>>(wx1, wy1, wx2, wy2, wnv, mask);
    scan_out_kernel<<<BB, NT, 0, stream>>>(proposals, cls, sord, wnv, mask, out);
}

// Round 4
// 199.141 us; speedup vs baseline: 8.3197x; 1.7586x over previous
//
#include <hip/hip_runtime.h>

typedef unsigned long long ull;

#define BB 16
#define NN 4096
#define NT 1024
#define EPT 4
#define MAXP 300
#define IOU_THRESH 0.7f
#define SCORE_THR 0.5f
#define WPR 64                  // 64-bit words per mask row

// mask kernel config
#define MBT 256                 // threads
#define MBPI 64                 // blocks per image
#define WPI (MBPI * (MBT / 64)) // 256 waves per image

// scan kernel config
#define SNT 512
#define SEPT (NN / SNT)         // 8 elements per thread

__device__ __forceinline__ bool iou_ge(float ix1, float iy1, float ix2, float iy2, float ia,
                                       float x1, float y1, float x2, float y2, float aj) {
    float xx1 = fmaxf(ix1, x1);
    float yy1 = fmaxf(iy1, y1);
    float xx2 = fminf(ix2, x2);
    float yy2 = fminf(iy2, y2);
    float iw = fmaxf(__fsub_rn(xx2, xx1), 0.0f);
    float ih = fmaxf(__fsub_rn(yy2, yy1), 0.0f);
    float inter = __fmul_rn(iw, ih);
    float uni = __fsub_rn(__fadd_rn(ia, aj), inter);
    float iou = __fdiv_rn(inter, uni);
    return iou >= IOU_THRESH;
}

// ---------------- Kernel A: key build + bitonic sort + SoA scatter ----------------
__global__ __launch_bounds__(NT) void sort_kernel(const float* __restrict__ proposals,
                                                  const float* __restrict__ cls,
                                                  float4* __restrict__ wbox,
                                                  float* __restrict__ war,
                                                  unsigned* __restrict__ sord,
                                                  unsigned* __restrict__ wnv) {
    __shared__ ull skeys[NN];
    __shared__ unsigned s_nvalid;
    const int b = blockIdx.x, tid = threadIdx.x;
    const float* Cb = cls + (size_t)b * NN * 2;
    const float4* Pb4 = (const float4*)(proposals + (size_t)b * NN * 4);

    if (tid == 0) s_nvalid = 0;
    __syncthreads();

    unsigned lv = 0;
    for (int i = tid; i < NN; i += NT) {
        float sc = Cb[i * 2 + 1];
        bool valid = sc > SCORE_THR;
        unsigned mb = valid ? (__float_as_uint(sc) | 0x80000000u) : 0u;
        skeys[i] = ((ull)mb << 32) | (unsigned)(~i);
        lv += valid ? 1u : 0u;
    }
    for (int off = 32; off > 0; off >>= 1) lv += __shfl_down(lv, off, 64);
    if ((tid & 63) == 0) atomicAdd(&s_nvalid, lv);

    // bitonic sort, descending; enumerate active pairs only
    for (unsigned k = 2; k <= NN; k <<= 1) {
        for (unsigned j = k >> 1; j > 0; j >>= 1) {
            __syncthreads();
            for (unsigned p = tid; p < NN / 2; p += NT) {
                unsigned low = p & (j - 1);
                unsigned i = ((p ^ low) << 1) | low;
                unsigned ixj = i | j;
                ull a = skeys[i], c = skeys[ixj];
                if ((a < c) == ((i & k) == 0)) { skeys[i] = c; skeys[ixj] = a; }
            }
        }
    }
    __syncthreads();

    const size_t base = (size_t)b * NN;
    for (int c = 0; c < EPT; ++c) {
        int j = tid * EPT + c;
        unsigned oi = ~(unsigned)skeys[j];
        sord[base + j] = oi;
        float4 v = Pb4[oi];
        wbox[base + j] = v;
        war[base + j] = __fmul_rn(__fsub_rn(v.z, v.x), __fsub_rn(v.w, v.y));
    }
    if (tid == 0) wnv[b] = s_nvalid;
}

// ---------------- Kernel B: suppression bit-matrix, whole GPU, no LDS ----------------
__global__ __launch_bounds__(MBT) void mask_kernel(const float4* __restrict__ wbox,
                                                   const float* __restrict__ war,
                                                   const unsigned* __restrict__ wnv,
                                                   ull* __restrict__ mask) {
    const int img = blockIdx.y;
    const unsigned nv = wnv[img];
    if (nv == 0) return;
    const unsigned lane = threadIdx.x & 63;
    const unsigned wave = threadIdx.x >> 6;
    const unsigned wid = blockIdx.x * (MBT / 64) + wave;
    const size_t base = (size_t)img * NN;
    const float4* bimg = wbox + base;
    const float* aimg = war + base;
    ull* mimg = mask + base * WPR;
    const unsigned wlast = (nv - 1) >> 6;

    for (unsigned i = wid; i < nv; i += WPI) {   // stride-interleaved: balances triangle
        float4 bi = bimg[i];
        float ia = aimg[i];
        const unsigned w0 = i >> 6;
        ull my = 0;
        #pragma unroll 2
        for (unsigned w = w0; w <= wlast; ++w) {
            unsigned jj = (w << 6) | lane;
            float4 bj = bimg[jj];
            float aj = aimg[jj];
            bool pred = (jj > i) && iou_ge(bi.x, bi.y, bi.z, bi.w, ia,
                                           bj.x, bj.y, bj.z, bj.w, aj);
            ull bal = __ballot(pred);
            if (lane == w) my = bal;
        }
        mimg[(size_t)i * WPR + lane] = my;       // full 512 B row, zeros outside [w0,wlast]
    }
}

// ---------------- Kernel C: serial OR-scan (32-deep dbuf prefetch) + output ----------------
__device__ __forceinline__ void pref32(ull (&buf)[32], const ull* __restrict__ mrow,
                                       unsigned g, unsigned lane) {
    unsigned rbase = g << 5;
    #pragma unroll
    for (int k = 0; k < 32; ++k)
        buf[k] = mrow[(size_t)(rbase + k) * WPR + lane];
}

__device__ __forceinline__ void proc32(ull (&buf)[32], ull& sup, unsigned g, unsigned lane) {
    unsigned ibase = g << 5;
    #pragma unroll
    for (int k = 0; k < 32; ++k) {
        unsigned i = ibase + k;
        bool kb = (lane == (i >> 6)) && (((sup >> (i & 63)) & 1ULL) == 0ULL);
        ull km = __ballot(kb);
        sup |= (km ? buf[k] : 0ULL);
    }
}

__global__ __launch_bounds__(SNT, 1) void scan_out_kernel(const float* __restrict__ proposals,
                                                          const float* __restrict__ cls,
                                                          const unsigned* __restrict__ sord,
                                                          const unsigned* __restrict__ wnv,
                                                          const ull* __restrict__ mask,
                                                          float* __restrict__ out) {
    __shared__ ull ssw[WPR];
    __shared__ unsigned ssel[MAXP];
    __shared__ unsigned swsum[SNT / 64];
    __shared__ unsigned s_nk;
    const int b = blockIdx.x, tid = threadIdx.x;
    const unsigned nv = wnv[b];
    const size_t base = (size_t)b * NN;
    const float* Pb = proposals + base * 4;
    const float* Cb = cls + base * 2;

    if (tid < 64) {
        const unsigned lane = tid;
        unsigned lb = lane << 6;
        ull sup;
        if (lb >= nv) sup = ~0ULL;
        else if (lb + 64 <= nv) sup = 0ULL;
        else sup = (~0ULL) << (nv - lb);

        if (nv > 0) {
            const ull* mrow = mask + base * WPR;
            ull bufA[32], bufB[32];
            const unsigned ng = (nv + 31) >> 5;
            pref32(bufA, mrow, 0, lane);
            unsigned g = 0;
            while (g < ng) {
                if (g + 1 < ng) pref32(bufB, mrow, g + 1, lane);
                proc32(bufA, sup, g, lane);
                if (g + 1 >= ng) break;
                if (g + 2 < ng) pref32(bufA, mrow, g + 2, lane);
                proc32(bufB, sup, g + 1, lane);
                g += 2;
            }
        }
        ssw[lane] = sup;
    }
    __syncthreads();

    // ---- prefix sum of keep flags -> ranks ----
    unsigned ordj[SEPT], kflag[SEPT];
    unsigned lc = 0;
    for (int c = 0; c < SEPT; ++c) {
        int j = tid * SEPT + c;
        ordj[c] = sord[base + j];
        unsigned bit = (unsigned)((ssw[j >> 6] >> (j & 63)) & 1ULL);
        kflag[c] = bit ^ 1u;
        lc += kflag[c];
    }
    unsigned lane = tid & 63, wid = tid >> 6;
    unsigned inc = lc;
    for (int off = 1; off < 64; off <<= 1) {
        unsigned o = __shfl_up(inc, off, 64);
        if (lane >= (unsigned)off) inc += o;
    }
    if (lane == 63) swsum[wid] = inc;
    __syncthreads();
    if (tid == 0) {
        unsigned run = 0;
        for (int w = 0; w < SNT / 64; ++w) { unsigned t = swsum[w]; swsum[w] = run; run += t; }
        s_nk = run;
    }
    __syncthreads();
    unsigned pos = swsum[wid] + (inc - lc);
    for (int c = 0; c < SEPT; ++c) {
        if (kflag[c]) {
            if (pos < MAXP) ssel[pos] = ordj[c];
            ++pos;
        }
    }
    const unsigned nk = s_nk;
    __syncthreads();

    if (tid < MAXP) {
        if (nk == 0) {
            ssel[tid] = sord[base + NN - 1];
        } else if (tid >= nk) {
            ssel[tid] = ssel[nk - 1];
        }
    }
    __syncthreads();

    if (tid < MAXP) {
        unsigned si = ssel[tid];
        const float* P = Pb + (size_t)si * 4;
        float* ob = out + ((size_t)b * MAXP + tid) * 4;
        ob[0] = P[0]; ob[1] = P[1]; ob[2] = P[2]; ob[3] = P[3];
        out[(size_t)BB * MAXP * 4 + (size_t)b * MAXP + tid] = Cb[si * 2 + 1];
    }
}

// ---------------- Fallback (round-2 monolithic, used if ws too small) ----------------
#define CH 64
#define TPC (CH / EPT)
__global__ __launch_bounds__(NT) void nms_fallback(const float* __restrict__ proposals,
                                                   const float* __restrict__ cls,
                                                   float* __restrict__ out) {
    __shared__ unsigned long long skeys[NN];
    __shared__ unsigned char ssup[NN];
    __shared__ float cbx1[2][CH], cby1[2][CH], cbx2[2][CH], cby2[2][CH], cbar[2][CH];
    __shared__ unsigned long long skept[2];
    __shared__ unsigned int ssel[MAXP];
    __shared__ unsigned int swsum[NT / 64];
    __shared__ unsigned int s_nvalid;
    __shared__ unsigned int s_nk;

    const int b = blockIdx.x;
    const int tid = threadIdx.x;
    const float* Pb = proposals + (size_t)b * NN * 4;
    const float* Cb = cls + (size_t)b * NN * 2;

    if (tid == 0) s_nvalid = 0;
    __syncthreads();

    unsigned lv = 0;
    for (int i = tid; i < NN; i += NT) {
        float sc = Cb[i * 2 + 1];
        bool valid = sc > SCORE_THR;
        unsigned mb = valid ? (__float_as_uint(sc) | 0x80000000u) : 0u;
        skeys[i] = ((unsigned long long)mb << 32) | (unsigned)(~i);
        lv += valid ? 1u : 0u;
    }
    for (int off = 32; off > 0; off >>= 1) lv += __shfl_down(lv, off, 64);
    if ((tid & 63) == 0) atomicAdd(&s_nvalid, lv);

    for (unsigned k = 2; k <= NN; k <<= 1) {
        for (unsigned j = k >> 1; j > 0; j >>= 1) {
            __syncthreads();
            for (unsigned i = tid; i < NN; i += NT) {
                unsigned ixj = i ^ j;
                if (ixj > i) {
                    unsigned long long a = skeys[i], c = skeys[ixj];
                    bool up = ((i & k) == 0);
                    if ((a < c) == up) { skeys[i] = c; skeys[ixj] = a; }
                }
            }
        }
    }
    __syncthreads();

    const unsigned n_valid = s_nvalid;

    unsigned ordj[EPT];
    float bx1[EPT], by1[EPT], bx2[EPT], by2[EPT], bar[EPT];
    int rflag[EPT];
    for (int c2 = 0; c2 < EPT; ++c2) {
        int j = tid * EPT + c2;
        unsigned oi = ~(unsigned)skeys[j];
        ordj[c2] = oi;
        const float* P = Pb + (size_t)oi * 4;
        float x1 = P[0], y1 = P[1], x2 = P[2], y2 = P[3];
        bx1[c2] = x1; by1[c2] = y1; bx2[c2] = x2; by2[c2] = y2;
        bar[c2] = __fmul_rn(__fsub_rn(x2, x1), __fsub_rn(y2, y1));
        int sup = (j < (int)n_valid) ? 0 : 1;
        rflag[c2] = sup;
        ssup[j] = (unsigned char)sup;
    }

    const unsigned nch = (n_valid + CH - 1) / CH;
    for (unsigned c = 0; c < nch; ++c) {
        const int p = (int)(c & 1);
        if (tid >= (int)(TPC * c) && tid < (int)(TPC * (c + 1))) {
            int bse = (tid - TPC * c) * EPT;
            #pragma unroll
            for (int c2 = 0; c2 < EPT; ++c2) {
                int l = bse + c2;
                cbx1[p][l] = bx1[c2]; cby1[p][l] = by1[c2];
                cbx2[p][l] = bx2[c2]; cby2[p][l] = by2[c2];
                cbar[p][l] = bar[c2];
            }
        }
        __syncthreads();

        if (tid < CH) {
            const int l = tid;
            const int j = (int)(c * CH) + l;
            float x1 = cbx1[p][l], y1 = cby1[p][l], x2 = cbx2[p][l], y2 = cby2[p][l];
            float ar = cbar[p][l];
            int supl = ssup[j];
            unsigned long long row = 0ULL;
            for (int m = l + 1; m < CH; ++m) {
                bool s = iou_ge(x1, y1, x2, y2, ar,
                                cbx1[p][m], cby1[p][m], cbx2[p][m], cby2[p][m], cbar[p][m]);
                if (s) row |= (1ULL << m);
            }
            unsigned long long S = __ballot(supl != 0);
            for (int i = 0; i < CH; ++i) {
                unsigned long long ri = __shfl(row, i, 64);
                if (!((S >> i) & 1ULL)) S |= ri;
            }
            ssup[j] = (unsigned char)((S >> l) & 1ULL);
            if (l == 0) skept[p] = ~S;
        }
        __syncthreads();

        const int myFirst = tid * EPT;
        if (myFirst >= (int)(CH * (c + 1)) &&
            !(rflag[0] & rflag[1] & rflag[2] & rflag[3])) {
            unsigned long long K = skept[p];
            while (K) {
                int m = __builtin_ctzll(K);
                K &= K - 1;
                float mx1 = cbx1[p][m], my1 = cby1[p][m];
                float mx2 = cbx2[p][m], my2 = cby2[p][m];
                float ma = cbar[p][m];
                #pragma unroll
                for (int c2 = 0; c2 < EPT; ++c2) {
                    if (!rflag[c2]) {
                        bool s = iou_ge(mx1, my1, mx2, my2, ma,
                                        bx1[c2], by1[c2], bx2[c2], by2[c2], bar[c2]);
                        if (s) { rflag[c2] = 1; ssup[myFirst + c2] = 1; }
                    }
                }
            }
        }
    }
    __syncthreads();

    unsigned kflag[EPT];
    unsigned lc = 0;
    for (int c2 = 0; c2 < EPT; ++c2) {
        int j = tid * EPT + c2;
        kflag[c2] = ssup[j] ? 0u : 1u;
        lc += kflag[c2];
    }
    unsigned lane = tid & 63, wid = tid >> 6;
    unsigned inc = lc;
    for (int off = 1; off < 64; off <<= 1) {
        unsigned o = __shfl_up(inc, off, 64);
        if (lane >= (unsigned)off) inc += o;
    }
    if (lane == 63) swsum[wid] = inc;
    __syncthreads();
    if (tid == 0) {
        unsigned run = 0;
        for (int w = 0; w < NT / 64; ++w) { unsigned t = swsum[w]; swsum[w] = run; run += t; }
        s_nk = run;
    }
    __syncthreads();
    unsigned bse = swsum[wid] + (inc - lc);
    for (int c2 = 0; c2 < EPT; ++c2) {
        if (kflag[c2]) {
            if (bse < MAXP) ssel[bse] = ordj[c2];
            ++bse;
        }
    }
    const unsigned nk_pre = s_nk;
    __syncthreads();

    if (tid < MAXP) {
        if (nk_pre == 0) {
            ssel[tid] = ~(unsigned)skeys[NN - 1];
        } else if (tid >= nk_pre) {
            ssel[tid] = ssel[nk_pre - 1];
        }
    }
    __syncthreads();

    if (tid < MAXP) {
        unsigned si = ssel[tid];
        const float* P = Pb + (size_t)si * 4;
        float* ob = out + ((size_t)b * MAXP + tid) * 4;
        ob[0] = P[0]; ob[1] = P[1]; ob[2] = P[2]; ob[3] = P[3];
        out[(size_t)BB * MAXP * 4 + (size_t)b * MAXP + tid] = Cb[si * 2 + 1];
    }
}

extern "C" void kernel_launch(void* const* d_in, const int* in_sizes, int n_in,
                              void* d_out, int out_size, void* d_ws, size_t ws_size,
                              hipStream_t stream) {
    const float* proposals = (const float*)d_in[0];
    const float* cls = (const float*)d_in[1];
    float* out = (float*)d_out;

    const size_t MASK_BYTES = (size_t)BB * NN * WPR * sizeof(ull);      // 32 MB
    const size_t SOA = (size_t)BB * NN;
    const size_t need = MASK_BYTES + SOA * sizeof(float4) + SOA * sizeof(float)
                      + SOA * sizeof(unsigned) + 256;

    if (ws_size < need) {
        nms_fallback<<<BB, NT, 0, stream>>>(proposals, cls, out);
        return;
    }

    ull* mask = (ull*)d_ws;
    float4* wbox = (float4*)((char*)d_ws + MASK_BYTES);
    float* war = (float*)(wbox + SOA);
    unsigned* sord = (unsigned*)(war + SOA);
    unsigned* wnv = sord + SOA;

    sort_kernel<<<BB, NT, 0, stream>>>(proposals, cls, wbox, war, sord, wnv);
    mask_kernel<<<dim3(MBPI, BB), MBT, 0, stream>>>(wbox, war, wnv, mask);
    scan_out_kernel<<<BB, SNT, 0, stream>>>(proposals, cls, sord, wnv, mask, out);
}

// Round 5
// 129.158 us; speedup vs baseline: 12.8277x; 1.5418x over previous
//
#include <hip/hip_runtime.h>

typedef unsigned long long ull;

#define BB 16
#define NN 4096
#define NT 1024
#define EPT 4
#define MAXP 300
#define IOU_THRESH 0.7f
#define SCORE_THR 0.5f
#define WPR 64                  // 64-bit words per mask row

// mask kernel config
#define MBT 256                 // threads
#define MBPI 64                 // blocks per image
#define WPI (MBPI * (MBT / 64)) // 256 waves per image

// scan kernel config
#define SNT 320                 // 5 waves; wave 0 scans, all gather
#define PD 16                   // prefetch depth (rows per group)

__device__ __forceinline__ bool iou_ge(float ix1, float iy1, float ix2, float iy2, float ia,
                                       float x1, float y1, float x2, float y2, float aj) {
    float xx1 = fmaxf(ix1, x1);
    float yy1 = fmaxf(iy1, y1);
    float xx2 = fminf(ix2, x2);
    float yy2 = fminf(iy2, y2);
    float iw = fmaxf(__fsub_rn(xx2, xx1), 0.0f);
    float ih = fmaxf(__fsub_rn(yy2, yy1), 0.0f);
    float inter = __fmul_rn(iw, ih);
    float uni = __fsub_rn(__fadd_rn(ia, aj), inter);
    float iou = __fdiv_rn(inter, uni);
    return iou >= IOU_THRESH;
}

// ---------------- Kernel A: key build + bitonic sort + SoA scatter ----------------
__global__ __launch_bounds__(NT) void sort_kernel(const float* __restrict__ proposals,
                                                  const float* __restrict__ cls,
                                                  float4* __restrict__ wbox,
                                                  float* __restrict__ war,
                                                  unsigned* __restrict__ sord,
                                                  unsigned* __restrict__ wnv) {
    __shared__ ull skeys[NN];
    __shared__ unsigned s_nvalid;
    const int b = blockIdx.x, tid = threadIdx.x;
    const float* Cb = cls + (size_t)b * NN * 2;
    const float4* Pb4 = (const float4*)(proposals + (size_t)b * NN * 4);

    if (tid == 0) s_nvalid = 0;
    __syncthreads();

    unsigned lv = 0;
    for (int i = tid; i < NN; i += NT) {
        float sc = Cb[i * 2 + 1];
        bool valid = sc > SCORE_THR;
        unsigned mb = valid ? (__float_as_uint(sc) | 0x80000000u) : 0u;
        skeys[i] = ((ull)mb << 32) | (unsigned)(~i);
        lv += valid ? 1u : 0u;
    }
    for (int off = 32; off > 0; off >>= 1) lv += __shfl_down(lv, off, 64);
    if ((tid & 63) == 0) atomicAdd(&s_nvalid, lv);

    // bitonic sort, descending; enumerate active pairs only
    for (unsigned k = 2; k <= NN; k <<= 1) {
        for (unsigned j = k >> 1; j > 0; j >>= 1) {
            __syncthreads();
            for (unsigned p = tid; p < NN / 2; p += NT) {
                unsigned low = p & (j - 1);
                unsigned i = ((p ^ low) << 1) | low;
                unsigned ixj = i | j;
                ull a = skeys[i], c = skeys[ixj];
                if ((a < c) == ((i & k) == 0)) { skeys[i] = c; skeys[ixj] = a; }
            }
        }
    }
    __syncthreads();

    const size_t base = (size_t)b * NN;
    for (int c = 0; c < EPT; ++c) {
        int j = tid * EPT + c;
        unsigned oi = ~(unsigned)skeys[j];
        sord[base + j] = oi;
        float4 v = Pb4[oi];
        wbox[base + j] = v;
        war[base + j] = __fmul_rn(__fsub_rn(v.z, v.x), __fsub_rn(v.w, v.y));
    }
    if (tid == 0) wnv[b] = s_nvalid;
}

// ---------------- Kernel B: suppression bit-matrix, whole GPU, no LDS ----------------
__global__ __launch_bounds__(MBT) void mask_kernel(const float4* __restrict__ wbox,
                                                   const float* __restrict__ war,
                                                   const unsigned* __restrict__ wnv,
                                                   ull* __restrict__ mask) {
    const int img = blockIdx.y;
    const unsigned nv = wnv[img];
    if (nv == 0) return;
    const unsigned lane = threadIdx.x & 63;
    const unsigned wave = threadIdx.x >> 6;
    const unsigned wid = blockIdx.x * (MBT / 64) + wave;
    const size_t base = (size_t)img * NN;
    const float4* bimg = wbox + base;
    const float* aimg = war + base;
    ull* mimg = mask + base * WPR;
    const unsigned wlast = (nv - 1) >> 6;

    for (unsigned i = wid; i < nv; i += WPI) {   // stride-interleaved: balances triangle
        float4 bi = bimg[i];
        float ia = aimg[i];
        const unsigned w0 = i >> 6;
        ull my = 0;
        #pragma unroll 2
        for (unsigned w = w0; w <= wlast; ++w) {
            unsigned jj = (w << 6) | lane;
            float4 bj = bimg[jj];
            float aj = aimg[jj];
            bool pred = (jj > i) && iou_ge(bi.x, bi.y, bi.z, bi.w, ia,
                                           bj.x, bj.y, bj.z, bj.w, aj);
            ull bal = __ballot(pred);
            if (lane == w) my = bal;
        }
        // store only the words that can be nonzero: [w0, wlast]
        if (lane >= w0 && lane <= wlast)
            mimg[(size_t)i * WPR + lane] = my;
    }
}

// ---------------- Kernel C: serial OR-scan, early-exit, direct selection ----------------
__device__ __forceinline__ void prefPD(ull (&buf)[PD], const ull* __restrict__ mrow,
                                       unsigned g, unsigned lane) {
    unsigned rbase = g * PD;
    #pragma unroll
    for (int k = 0; k < PD; ++k)
        buf[k] = mrow[(size_t)(rbase + k) * WPR + lane];
}

__device__ __forceinline__ bool procPD(ull (&buf)[PD], ull& sup, unsigned g, unsigned lane,
                                       unsigned& cnt, unsigned* __restrict__ ssel) {
    unsigned ibase = g * PD;
    #pragma unroll
    for (int k = 0; k < PD; ++k) {
        unsigned i = ibase + k;
        bool kb = (lane == (i >> 6)) && (((sup >> (i & 63)) & 1ULL) == 0ULL);
        ull km = __ballot(kb);
        if (km) {                                  // wave-uniform
            if (lane == 0) ssel[cnt] = i;          // record sorted position of cnt-th kept
            ++cnt;
            sup |= (lane >= (i >> 6)) ? buf[k] : 0ULL;  // guard unwritten words < w0
            if (cnt == MAXP) return true;
        }
    }
    return false;
}

__global__ __launch_bounds__(SNT, 1) void scan_out_kernel(const float* __restrict__ proposals,
                                                          const float* __restrict__ cls,
                                                          const unsigned* __restrict__ sord,
                                                          const unsigned* __restrict__ wnv,
                                                          const ull* __restrict__ mask,
                                                          float* __restrict__ out) {
    __shared__ unsigned ssel[MAXP];
    __shared__ unsigned s_nk;
    const int b = blockIdx.x, tid = threadIdx.x;
    const unsigned nv = wnv[b];
    const size_t base = (size_t)b * NN;
    const float* Pb = proposals + base * 4;
    const float* Cb = cls + base * 2;

    if (tid < 64) {
        const unsigned lane = tid;
        unsigned lb = lane << 6;
        ull sup;
        if (lb >= nv) sup = ~0ULL;
        else if (lb + 64 <= nv) sup = 0ULL;
        else sup = (~0ULL) << (nv - lb);

        unsigned cnt = 0;
        if (nv > 0) {
            const ull* mrow = mask + base * WPR;
            ull bufA[PD], bufB[PD];
            const unsigned ng = (nv + PD - 1) / PD;
            unsigned g = 0;
            prefPD(bufA, mrow, 0, lane);
            while (true) {
                if (g + 1 < ng) prefPD(bufB, mrow, g + 1, lane);
                if (procPD(bufA, sup, g, lane, cnt, ssel)) break;
                if (++g >= ng) break;
                if (g + 1 < ng) prefPD(bufA, mrow, g + 1, lane);
                if (procPD(bufB, sup, g, lane, cnt, ssel)) break;
                if (++g >= ng) break;
            }
        }
        if (lane == 0) s_nk = cnt;
    }
    __syncthreads();

    if (tid < MAXP) {
        const unsigned nk = s_nk;
        unsigned p;                                // sorted position
        if (nk == 0) p = NN - 1;                   // matches reference clip semantics
        else p = ssel[tid < nk ? tid : nk - 1];
        unsigned si = sord[base + p];
        const float* P = Pb + (size_t)si * 4;
        float* ob = out + ((size_t)b * MAXP + tid) * 4;
        ob[0] = P[0]; ob[1] = P[1]; ob[2] = P[2]; ob[3] = P[3];
        out[(size_t)BB * MAXP * 4 + (size_t)b * MAXP + tid] = Cb[si * 2 + 1];
    }
}

// ---------------- Fallback (round-2 monolithic, used if ws too small) ----------------
#define CH 64
#define TPC (CH / EPT)
__global__ __launch_bounds__(NT) void nms_fallback(const float* __restrict__ proposals,
                                                   const float* __restrict__ cls,
                                                   float* __restrict__ out) {
    __shared__ unsigned long long skeys[NN];
    __shared__ unsigned char ssup[NN];
    __shared__ float cbx1[2][CH], cby1[2][CH], cbx2[2][CH], cby2[2][CH], cbar[2][CH];
    __shared__ unsigned long long skept[2];
    __shared__ unsigned int ssel[MAXP];
    __shared__ unsigned int swsum[NT / 64];
    __shared__ unsigned int s_nvalid;
    __shared__ unsigned int s_nk;

    const int b = blockIdx.x;
    const int tid = threadIdx.x;
    const float* Pb = proposals + (size_t)b * NN * 4;
    const float* Cb = cls + (size_t)b * NN * 2;

    if (tid == 0) s_nvalid = 0;
    __syncthreads();

    unsigned lv = 0;
    for (int i = tid; i < NN; i += NT) {
        float sc = Cb[i * 2 + 1];
        bool valid = sc > SCORE_THR;
        unsigned mb = valid ? (__float_as_uint(sc) | 0x80000000u) : 0u;
        skeys[i] = ((unsigned long long)mb << 32) | (unsigned)(~i);
        lv += valid ? 1u : 0u;
    }
    for (int off = 32; off > 0; off >>= 1) lv += __shfl_down(lv, off, 64);
    if ((tid & 63) == 0) atomicAdd(&s_nvalid, lv);

    for (unsigned k = 2; k <= NN; k <<= 1) {
        for (unsigned j = k >> 1; j > 0; j >>= 1) {
            __syncthreads();
            for (unsigned i = tid; i < NN; i += NT) {
                unsigned ixj = i ^ j;
                if (ixj > i) {
                    unsigned long long a = skeys[i], c = skeys[ixj];
                    bool up = ((i & k) == 0);
                    if ((a < c) == up) { skeys[i] = c; skeys[ixj] = a; }
                }
            }
        }
    }
    __syncthreads();

    const unsigned n_valid = s_nvalid;

    unsigned ordj[EPT];
    float bx1[EPT], by1[EPT], bx2[EPT], by2[EPT], bar[EPT];
    int rflag[EPT];
    for (int c2 = 0; c2 < EPT; ++c2) {
        int j = tid * EPT + c2;
        unsigned oi = ~(unsigned)skeys[j];
        ordj[c2] = oi;
        const float* P = Pb + (size_t)oi * 4;
        float x1 = P[0], y1 = P[1], x2 = P[2], y2 = P[3];
        bx1[c2] = x1; by1[c2] = y1; bx2[c2] = x2; by2[c2] = y2;
        bar[c2] = __fmul_rn(__fsub_rn(x2, x1), __fsub_rn(y2, y1));
        int sup = (j < (int)n_valid) ? 0 : 1;
        rflag[c2] = sup;
        ssup[j] = (unsigned char)sup;
    }

    const unsigned nch = (n_valid + CH - 1) / CH;
    for (unsigned c = 0; c < nch; ++c) {
        const int p = (int)(c & 1);
        if (tid >= (int)(TPC * c) && tid < (int)(TPC * (c + 1))) {
            int bse = (tid - TPC * c) * EPT;
            #pragma unroll
            for (int c2 = 0; c2 < EPT; ++c2) {
                int l = bse + c2;
                cbx1[p][l] = bx1[c2]; cby1[p][l] = by1[c2];
                cbx2[p][l] = bx2[c2]; cby2[p][l] = by2[c2];
                cbar[p][l] = bar[c2];
            }
        }
        __syncthreads();

        if (tid < CH) {
            const int l = tid;
            const int j = (int)(c * CH) + l;
            float x1 = cbx1[p][l], y1 = cby1[p][l], x2 = cbx2[p][l], y2 = cby2[p][l];
            float ar = cbar[p][l];
            int supl = ssup[j];
            unsigned long long row = 0ULL;
            for (int m = l + 1; m < CH; ++m) {
                bool s = iou_ge(x1, y1, x2, y2, ar,
                                cbx1[p][m], cby1[p][m], cbx2[p][m], cby2[p][m], cbar[p][m]);
                if (s) row |= (1ULL << m);
            }
            unsigned long long S = __ballot(supl != 0);
            for (int i = 0; i < CH; ++i) {
                unsigned long long ri = __shfl(row, i, 64);
                if (!((S >> i) & 1ULL)) S |= ri;
            }
            ssup[j] = (unsigned char)((S >> l) & 1ULL);
            if (l == 0) skept[p] = ~S;
        }
        __syncthreads();

        const int myFirst = tid * EPT;
        if (myFirst >= (int)(CH * (c + 1)) &&
            !(rflag[0] & rflag[1] & rflag[2] & rflag[3])) {
            unsigned long long K = skept[p];
            while (K) {
                int m = __builtin_ctzll(K);
                K &= K - 1;
                float mx1 = cbx1[p][m], my1 = cby1[p][m];
                float mx2 = cbx2[p][m], my2 = cby2[p][m];
                float ma = cbar[p][m];
                #pragma unroll
                for (int c2 = 0; c2 < EPT; ++c2) {
                    if (!rflag[c2]) {
                        bool s = iou_ge(mx1, my1, mx2, my2, ma,
                                        bx1[c2], by1[c2], bx2[c2], by2[c2], bar[c2]);
                        if (s) { rflag[c2] = 1; ssup[myFirst + c2] = 1; }
                    }
                }
            }
        }
    }
    __syncthreads();

    unsigned kflag[EPT];
    unsigned lc = 0;
    for (int c2 = 0; c2 < EPT; ++c2) {
        int j = tid * EPT + c2;
        kflag[c2] = ssup[j] ? 0u : 1u;
        lc += kflag[c2];
    }
    unsigned lane = tid & 63, wid = tid >> 6;
    unsigned inc = lc;
    for (int off = 1; off < 64; off <<= 1) {
        unsigned o = __shfl_up(inc, off, 64);
        if (lane >= (unsigned)off) inc += o;
    }
    if (lane == 63) swsum[wid] = inc;
    __syncthreads();
    if (tid == 0) {
        unsigned run = 0;
        for (int w = 0; w < NT / 64; ++w) { unsigned t = swsum[w]; swsum[w] = run; run += t; }
        s_nk = run;
    }
    __syncthreads();
    unsigned bse = swsum[wid] + (inc - lc);
    for (int c2 = 0; c2 < EPT; ++c2) {
        if (kflag[c2]) {
            if (bse < MAXP) ssel[bse] = ordj[c2];
            ++bse;
        }
    }
    const unsigned nk_pre = s_nk;
    __syncthreads();

    if (tid < MAXP) {
        if (nk_pre == 0) {
            ssel[tid] = ~(unsigned)skeys[NN - 1];
        } else if (tid >= nk_pre) {
            ssel[tid] = ssel[nk_pre - 1];
        }
    }
    __syncthreads();

    if (tid < MAXP) {
        unsigned si = ssel[tid];
        const float* P = Pb + (size_t)si * 4;
        float* ob = out + ((size_t)b * MAXP + tid) * 4;
        ob[0] = P[0]; ob[1] = P[1]; ob[2] = P[2]; ob[3] = P[3];
        out[(size_t)BB * MAXP * 4 + (size_t)b * MAXP + tid] = Cb[si * 2 + 1];
    }
}

extern "C" void kernel_launch(void* const* d_in, const int* in_sizes, int n_in,
                              void* d_out, int out_size, void* d_ws, size_t ws_size,
                              hipStream_t stream) {
    const float* proposals = (const float*)d_in[0];
    const float* cls = (const float*)d_in[1];
    float* out = (float*)d_out;

    const size_t MASK_BYTES = (size_t)BB * NN * WPR * sizeof(ull);      // 32 MB
    const size_t SOA = (size_t)BB * NN;
    const size_t need = MASK_BYTES + SOA * sizeof(float4) + SOA * sizeof(float)
                      + SOA * sizeof(unsigned) + 256;

    if (ws_size < need) {
        nms_fallback<<<BB, NT, 0, stream>>>(proposals, cls, out);
        return;
    }

    ull* mask = (ull*)d_ws;
    float4* wbox = (float4*)((char*)d_ws + MASK_BYTES);
    float* war = (float*)(wbox + SOA);
    unsigned* sord = (unsigned*)(war + SOA);
    unsigned* wnv = sord + SOA;

    sort_kernel<<<BB, NT, 0, stream>>>(proposals, cls, wbox, war, sord, wnv);
    mask_kernel<<<dim3(MBPI, BB), MBT, 0, stream>>>(wbox, war, wnv, mask);
    scan_out_kernel<<<BB, SNT, 0, stream>>>(proposals, cls, sord, wnv, mask, out);
}

// Round 6
// 115.633 us; speedup vs baseline: 14.3280x; 1.1170x over previous
//
#include <hip/hip_runtime.h>

typedef unsigned long long ull;

#define BB 16
#define NN 4096
#define NT 1024
#define EPT 4
#define MAXP 300
#define IOU_THRESH 0.7f
#define SCORE_THR 0.5f

#define RTOP 512               // fast-path window (sorted rows/cols)
#define RW (RTOP / 64)         // 8 mask words per row in fast path

// phase-2 (full) configs — round-5 validated
#define WPR 64
#define MBT 256
#define MBPI 64
#define WPI (MBPI * (MBT / 64))
#define SNT 320
#define PD 16

__device__ __forceinline__ bool iou_ge(float ix1, float iy1, float ix2, float iy2, float ia,
                                       float x1, float y1, float x2, float y2, float aj) {
    float xx1 = fmaxf(ix1, x1);
    float yy1 = fmaxf(iy1, y1);
    float xx2 = fminf(ix2, x2);
    float yy2 = fminf(iy2, y2);
    float iw = fmaxf(__fsub_rn(xx2, xx1), 0.0f);
    float ih = fmaxf(__fsub_rn(yy2, yy1), 0.0f);
    float inter = __fmul_rn(iw, ih);
    float uni = __fsub_rn(__fadd_rn(ia, aj), inter);
    float iou = __fdiv_rn(inter, uni);
    return iou >= IOU_THRESH;
}

__device__ __forceinline__ void cswap(ull& a, ull& b, bool up) {
    bool sw = (a < b) == up;          // up: ensure a >= b (descending)
    if (sw) { ull t = a; a = b; b = t; }
}

// ================= Fused fast-path kernel =================
__global__ __launch_bounds__(NT) void fused_kernel(const float* __restrict__ proposals,
                                                   const float* __restrict__ cls,
                                                   unsigned* __restrict__ sord,
                                                   unsigned* __restrict__ wnv,
                                                   unsigned* __restrict__ need,
                                                   float* __restrict__ out) {
    __shared__ ull skeys[NN];                       // 32 KB; reused as mask[RTOP][RW]
    __shared__ float sx1[RTOP], sy1[RTOP], sx2[RTOP], sy2[RTOP], sar[RTOP];  // 10 KB
    __shared__ unsigned stop_oi[RTOP];              // 2 KB
    __shared__ unsigned ssel[MAXP];
    __shared__ unsigned s_nvalid, s_nk, s_last;

    const int b = blockIdx.x, tid = threadIdx.x;
    const float* Cb = cls + (size_t)b * NN * 2;
    const float4* Pb4 = (const float4*)(proposals + (size_t)b * NN * 4);
    const size_t base = (size_t)b * NN;

    if (tid == 0) s_nvalid = 0;
    __syncthreads();

    // ---- build keys in registers ----
    ull e[4];
    unsigned lv = 0;
    #pragma unroll
    for (int c = 0; c < 4; ++c) {
        int i = tid * 4 + c;
        float sc = Cb[i * 2 + 1];
        bool valid = sc > SCORE_THR;
        unsigned mb = valid ? (__float_as_uint(sc) | 0x80000000u) : 0u;
        e[c] = ((ull)mb << 32) | (unsigned)(~i);
        lv += valid ? 1u : 0u;
    }
    for (int off = 32; off > 0; off >>= 1) lv += __shfl_down(lv, off, 64);
    if ((tid & 63) == 0) atomicAdd(&s_nvalid, lv);

    // ---- bitonic sort: registers + shfl; LDS only for j>=256 (10 stages) ----
    // k = 2
    cswap(e[0], e[1], true);
    cswap(e[2], e[3], false);
    for (unsigned k = 4; k <= NN; k <<= 1) {
        const bool up = ((tid * 4u & k) == 0);      // uniform per thread (k >= 4)
        for (unsigned j = k >> 1; j >= 256; j >>= 1) {          // LDS stages
            #pragma unroll
            for (int c = 0; c < 4; ++c) skeys[tid * 4 + c] = e[c];
            __syncthreads();
            unsigned d = j >> 2;
            unsigned pt = tid ^ d;
            bool upper = (tid & d) != 0;
            #pragma unroll
            for (int c = 0; c < 4; ++c) {
                ull o = skeys[pt * 4 + c];
                ull mn = (e[c] < o) ? e[c] : o;
                ull mx = (e[c] < o) ? o : e[c];
                e[c] = (up ^ upper) ? mx : mn;
            }
            __syncthreads();
        }
        for (unsigned j = ((k >> 1) > 128u ? 128u : (k >> 1)); j >= 4; j >>= 1) {  // shfl stages
            unsigned d = j >> 2;
            bool upper = (tid & d) != 0;
            #pragma unroll
            for (int c = 0; c < 4; ++c) {
                ull o = __shfl_xor(e[c], (int)d, 64);
                ull mn = (e[c] < o) ? e[c] : o;
                ull mx = (e[c] < o) ? o : e[c];
                e[c] = (up ^ upper) ? mx : mn;
            }
        }
        cswap(e[0], e[2], up); cswap(e[1], e[3], up);   // j = 2
        cswap(e[0], e[1], up); cswap(e[2], e[3], up);   // j = 1
    }

    // ---- scatter sorted order; stash last; fill top-RTOP SoA ----
    #pragma unroll
    for (int c = 0; c < 4; ++c) sord[base + tid * 4 + c] = ~(unsigned)e[c];
    if (tid == NT - 1) s_last = ~(unsigned)e[3];
    if (tid < RTOP / 4) {
        #pragma unroll
        for (int c = 0; c < 4; ++c) {
            int i = tid * 4 + c;
            unsigned oi = ~(unsigned)e[c];
            stop_oi[i] = oi;
            float4 v = Pb4[oi];
            sx1[i] = v.x; sy1[i] = v.y; sx2[i] = v.z; sy2[i] = v.w;
            sar[i] = __fmul_rn(__fsub_rn(v.z, v.x), __fsub_rn(v.w, v.y));
        }
    }
    __syncthreads();

    const unsigned nv = s_nvalid;
    if (tid == 0) wnv[b] = nv;
    const unsigned R2 = nv < RTOP ? nv : RTOP;

    // ---- mask-gen into skeys-as-mask (512x512 bits) ----
    ull (*smask)[RW] = (ull(*)[RW])skeys;
    {
        const unsigned lane = tid & 63, wave = tid >> 6;
        const unsigned wlastR = R2 ? (R2 - 1) >> 6 : 0;
        for (unsigned i = wave; i < R2; i += NT / 64) {
            float ix1 = sx1[i], iy1 = sy1[i], ix2 = sx2[i], iy2 = sy2[i], ia = sar[i];
            const unsigned w0 = i >> 6;
            ull my = 0;
            for (unsigned w = w0; w <= wlastR; ++w) {
                unsigned jj = (w << 6) | lane;
                bool pred = (jj > i) && iou_ge(ix1, iy1, ix2, iy2, ia,
                                               sx1[jj], sy1[jj], sx2[jj], sy2[jj], sar[jj]);
                ull bal = __ballot(pred);
                if (lane == w) my = bal;
            }
            if (lane >= w0 && lane < RW) smask[i][lane] = my;
        }
    }
    __syncthreads();

    // ---- greedy OR-scan (wave 0), early-exit at MAXP ----
    if (tid < 64) {
        const unsigned lane = tid;
        unsigned lb = lane << 6;
        ull sup;
        if (lb >= nv) sup = ~0ULL;
        else if (lb + 64 <= nv) sup = 0ULL;
        else sup = (~0ULL) << (nv - lb);

        unsigned cnt = 0;
        if (R2 > 0) {
            auto ldrow = [&](unsigned g) -> ull {
                unsigned rr = g * 8 + (lane >> 3);
                if (rr >= RTOP) rr = 0;
                return smask[rr][lane & 7];
            };
            const unsigned ng = (R2 + 7) >> 3;
            ull bufA = ldrow(0), bufB = 0;
            for (unsigned g = 0; g < ng && cnt < MAXP; ++g) {
                if (g + 1 < ng) bufB = ldrow(g + 1);
                #pragma unroll
                for (int k2 = 0; k2 < 8; ++k2) {
                    unsigned i = g * 8 + (unsigned)k2;
                    if (i >= R2) break;                         // wave-uniform
                    bool kb = (lane == (i >> 6)) && (((sup >> (i & 63)) & 1ULL) == 0ULL);
                    ull km = __ballot(kb);
                    if (km) {                                    // wave-uniform
                        if (lane == 0) ssel[cnt] = i;
                        ++cnt;
                        ull rw = __shfl(bufA, (int)(((i & 7) << 3) | (lane & 7)), 64);
                        if (lane >= (i >> 6) && lane < RW) sup |= rw;
                        if (cnt == MAXP) break;
                    }
                }
                bufA = bufB;
            }
        }
        if (lane == 0) {
            s_nk = cnt;
            need[b] = (cnt < MAXP && nv > RTOP) ? 1u : 0u;
        }
    }
    __syncthreads();

    // ---- output (overwritten by phase-2 if need) ----
    const unsigned nk = s_nk;
    if (tid < MAXP) {
        unsigned p = (nk == 0) ? (NN - 1) : ssel[tid < nk ? tid : nk - 1];
        unsigned oi;
        float x1, y1, x2, y2;
        if (p < RTOP) {
            oi = stop_oi[p];
            x1 = sx1[p]; y1 = sy1[p]; x2 = sx2[p]; y2 = sy2[p];
        } else {
            oi = s_last;                 // only reachable when nk==0 -> p = NN-1
            float4 v = Pb4[oi];
            x1 = v.x; y1 = v.y; x2 = v.z; y2 = v.w;
        }
        float sc = Cb[oi * 2 + 1];
        float* ob = out + ((size_t)b * MAXP + tid) * 4;
        ob[0] = x1; ob[1] = y1; ob[2] = x2; ob[3] = y2;
        out[(size_t)BB * MAXP * 4 + (size_t)b * MAXP + tid] = sc;
    }
}

// ================= Phase-2 (rare) : flag-guarded full pipeline =================
__global__ __launch_bounds__(NT) void scatter_kernel(const float* __restrict__ proposals,
                                                     const unsigned* __restrict__ sord,
                                                     const unsigned* __restrict__ need,
                                                     float4* __restrict__ wbox,
                                                     float* __restrict__ war) {
    const int b = blockIdx.x;
    if (!need[b]) return;
    const int tid = threadIdx.x;
    const size_t base = (size_t)b * NN;
    const float4* Pb4 = (const float4*)(proposals + base * 4);
    #pragma unroll
    for (int c = 0; c < 4; ++c) {
        int j = tid * 4 + c;
        unsigned oi = sord[base + j];
        float4 v = Pb4[oi];
        wbox[base + j] = v;
        war[base + j] = __fmul_rn(__fsub_rn(v.z, v.x), __fsub_rn(v.w, v.y));
    }
}

__global__ __launch_bounds__(MBT) void mask_kernel(const float4* __restrict__ wbox,
                                                   const float* __restrict__ war,
                                                   const unsigned* __restrict__ wnv,
                                                   const unsigned* __restrict__ need,
                                                   ull* __restrict__ mask) {
    const int img = blockIdx.y;
    if (!need[img]) return;
    const unsigned nv = wnv[img];
    if (nv == 0) return;
    const unsigned lane = threadIdx.x & 63;
    const unsigned wave = threadIdx.x >> 6;
    const unsigned wid = blockIdx.x * (MBT / 64) + wave;
    const size_t base = (size_t)img * NN;
    const float4* bimg = wbox + base;
    const float* aimg = war + base;
    ull* mimg = mask + base * WPR;
    const unsigned wlast = (nv - 1) >> 6;

    for (unsigned i = wid; i < nv; i += WPI) {
        float4 bi = bimg[i];
        float ia = aimg[i];
        const unsigned w0 = i >> 6;
        ull my = 0;
        #pragma unroll 2
        for (unsigned w = w0; w <= wlast; ++w) {
            unsigned jj = (w << 6) | lane;
            float4 bj = bimg[jj];
            float aj = aimg[jj];
            bool pred = (jj > i) && iou_ge(bi.x, bi.y, bi.z, bi.w, ia,
                                           bj.x, bj.y, bj.z, bj.w, aj);
            ull bal = __ballot(pred);
            if (lane == w) my = bal;
        }
        if (lane >= w0 && lane <= wlast)
            mimg[(size_t)i * WPR + lane] = my;
    }
}

__device__ __forceinline__ void prefPD(ull (&buf)[PD], const ull* __restrict__ mrow,
                                       unsigned g, unsigned lane) {
    unsigned rbase = g * PD;
    #pragma unroll
    for (int k = 0; k < PD; ++k)
        buf[k] = mrow[(size_t)(rbase + k) * WPR + lane];
}

__device__ __forceinline__ bool procPD(ull (&buf)[PD], ull& sup, unsigned g, unsigned lane,
                                       unsigned& cnt, unsigned* __restrict__ ssel) {
    unsigned ibase = g * PD;
    #pragma unroll
    for (int k = 0; k < PD; ++k) {
        unsigned i = ibase + k;
        bool kb = (lane == (i >> 6)) && (((sup >> (i & 63)) & 1ULL) == 0ULL);
        ull km = __ballot(kb);
        if (km) {
            if (lane == 0) ssel[cnt] = i;
            ++cnt;
            sup |= (lane >= (i >> 6)) ? buf[k] : 0ULL;
            if (cnt == MAXP) return true;
        }
    }
    return false;
}

__global__ __launch_bounds__(SNT, 1) void scan_out_kernel(const float* __restrict__ proposals,
                                                          const float* __restrict__ cls,
                                                          const unsigned* __restrict__ sord,
                                                          const unsigned* __restrict__ wnv,
                                                          const unsigned* __restrict__ need,
                                                          const ull* __restrict__ mask,
                                                          float* __restrict__ out) {
    __shared__ unsigned ssel[MAXP];
    __shared__ unsigned s_nk;
    const int b = blockIdx.x, tid = threadIdx.x;
    if (!need[b]) return;
    const unsigned nv = wnv[b];
    const size_t base = (size_t)b * NN;
    const float* Pb = proposals + base * 4;
    const float* Cb = cls + base * 2;

    if (tid < 64) {
        const unsigned lane = tid;
        unsigned lb = lane << 6;
        ull sup;
        if (lb >= nv) sup = ~0ULL;
        else if (lb + 64 <= nv) sup = 0ULL;
        else sup = (~0ULL) << (nv - lb);

        unsigned cnt = 0;
        if (nv > 0) {
            const ull* mrow = mask + base * WPR;
            ull bufA[PD], bufB[PD];
            const unsigned ng = (nv + PD - 1) / PD;
            unsigned g = 0;
            prefPD(bufA, mrow, 0, lane);
            while (true) {
                if (g + 1 < ng) prefPD(bufB, mrow, g + 1, lane);
                if (procPD(bufA, sup, g, lane, cnt, ssel)) break;
                if (++g >= ng) break;
                if (g + 1 < ng) prefPD(bufA, mrow, g + 1, lane);
                if (procPD(bufB, sup, g, lane, cnt, ssel)) break;
                if (++g >= ng) break;
            }
        }
        if (lane == 0) s_nk = cnt;
    }
    __syncthreads();

    if (tid < MAXP) {
        const unsigned nk = s_nk;
        unsigned p;
        if (nk == 0) p = NN - 1;
        else p = ssel[tid < nk ? tid : nk - 1];
        unsigned si = sord[base + p];
        const float* P = Pb + (size_t)si * 4;
        float* ob = out + ((size_t)b * MAXP + tid) * 4;
        ob[0] = P[0]; ob[1] = P[1]; ob[2] = P[2]; ob[3] = P[3];
        out[(size_t)BB * MAXP * 4 + (size_t)b * MAXP + tid] = Cb[si * 2 + 1];
    }
}

// ================= Fallback (round-2 monolithic, used if ws too small) =================
#define CH 64
#define TPC (CH / EPT)
__global__ __launch_bounds__(NT) void nms_fallback(const float* __restrict__ proposals,
                                                   const float* __restrict__ cls,
                                                   float* __restrict__ out) {
    __shared__ unsigned long long skeys[NN];
    __shared__ unsigned char ssup[NN];
    __shared__ float cbx1[2][CH], cby1[2][CH], cbx2[2][CH], cby2[2][CH], cbar[2][CH];
    __shared__ unsigned long long skept[2];
    __shared__ unsigned int ssel[MAXP];
    __shared__ unsigned int swsum[NT / 64];
    __shared__ unsigned int s_nvalid;
    __shared__ unsigned int s_nk;

    const int b = blockIdx.x;
    const int tid = threadIdx.x;
    const float* Pb = proposals + (size_t)b * NN * 4;
    const float* Cb = cls + (size_t)b * NN * 2;

    if (tid == 0) s_nvalid = 0;
    __syncthreads();

    unsigned lv = 0;
    for (int i = tid; i < NN; i += NT) {
        float sc = Cb[i * 2 + 1];
        bool valid = sc > SCORE_THR;
        unsigned mb = valid ? (__float_as_uint(sc) | 0x80000000u) : 0u;
        skeys[i] = ((unsigned long long)mb << 32) | (unsigned)(~i);
        lv += valid ? 1u : 0u;
    }
    for (int off = 32; off > 0; off >>= 1) lv += __shfl_down(lv, off, 64);
    if ((tid & 63) == 0) atomicAdd(&s_nvalid, lv);

    for (unsigned k = 2; k <= NN; k <<= 1) {
        for (unsigned j = k >> 1; j > 0; j >>= 1) {
            __syncthreads();
            for (unsigned i = tid; i < NN; i += NT) {
                unsigned ixj = i ^ j;
                if (ixj > i) {
                    unsigned long long a = skeys[i], c = skeys[ixj];
                    bool up = ((i & k) == 0);
                    if ((a < c) == up) { skeys[i] = c; skeys[ixj] = a; }
                }
            }
        }
    }
    __syncthreads();

    const unsigned n_valid = s_nvalid;

    unsigned ordj[EPT];
    float bx1[EPT], by1[EPT], bx2[EPT], by2[EPT], bar[EPT];
    int rflag[EPT];
    for (int c2 = 0; c2 < EPT; ++c2) {
        int j = tid * EPT + c2;
        unsigned oi = ~(unsigned)skeys[j];
        ordj[c2] = oi;
        const float* P = Pb + (size_t)oi * 4;
        float x1 = P[0], y1 = P[1], x2 = P[2], y2 = P[3];
        bx1[c2] = x1; by1[c2] = y1; bx2[c2] = x2; by2[c2] = y2;
        bar[c2] = __fmul_rn(__fsub_rn(x2, x1), __fsub_rn(y2, y1));
        int sup = (j < (int)n_valid) ? 0 : 1;
        rflag[c2] = sup;
        ssup[j] = (unsigned char)sup;
    }

    const unsigned nch = (n_valid + CH - 1) / CH;
    for (unsigned c = 0; c < nch; ++c) {
        const int p = (int)(c & 1);
        if (tid >= (int)(TPC * c) && tid < (int)(TPC * (c + 1))) {
            int bse = (tid - TPC * c) * EPT;
            #pragma unroll
            for (int c2 = 0; c2 < EPT; ++c2) {
                int l = bse + c2;
                cbx1[p][l] = bx1[c2]; cby1[p][l] = by1[c2];
                cbx2[p][l] = bx2[c2]; cby2[p][l] = by2[c2];
                cbar[p][l] = bar[c2];
            }
        }
        __syncthreads();

        if (tid < CH) {
            const int l = tid;
            const int j = (int)(c * CH) + l;
            float x1 = cbx1[p][l], y1 = cby1[p][l], x2 = cbx2[p][l], y2 = cby2[p][l];
            float ar = cbar[p][l];
            int supl = ssup[j];
            unsigned long long row = 0ULL;
            for (int m = l + 1; m < CH; ++m) {
                bool s = iou_ge(x1, y1, x2, y2, ar,
                                cbx1[p][m], cby1[p][m], cbx2[p][m], cby2[p][m], cbar[p][m]);
                if (s) row |= (1ULL << m);
            }
            unsigned long long S = __ballot(supl != 0);
            for (int i = 0; i < CH; ++i) {
                unsigned long long ri = __shfl(row, i, 64);
                if (!((S >> i) & 1ULL)) S |= ri;
            }
            ssup[j] = (unsigned char)((S >> l) & 1ULL);
            if (l == 0) skept[p] = ~S;
        }
        __syncthreads();

        const int myFirst = tid * EPT;
        if (myFirst >= (int)(CH * (c + 1)) &&
            !(rflag[0] & rflag[1] & rflag[2] & rflag[3])) {
            unsigned long long K = skept[p];
            while (K) {
                int m = __builtin_ctzll(K);
                K &= K - 1;
                float mx1 = cbx1[p][m], my1 = cby1[p][m];
                float mx2 = cbx2[p][m], my2 = cby2[p][m];
                float ma = cbar[p][m];
                #pragma unroll
                for (int c2 = 0; c2 < EPT; ++c2) {
                    if (!rflag[c2]) {
                        bool s = iou_ge(mx1, my1, mx2, my2, ma,
                                        bx1[c2], by1[c2], bx2[c2], by2[c2], bar[c2]);
                        if (s) { rflag[c2] = 1; ssup[myFirst + c2] = 1; }
                    }
                }
            }
        }
    }
    __syncthreads();

    unsigned kflag[EPT];
    unsigned lc = 0;
    for (int c2 = 0; c2 < EPT; ++c2) {
        int j = tid * EPT + c2;
        kflag[c2] = ssup[j] ? 0u : 1u;
        lc += kflag[c2];
    }
    unsigned lane = tid & 63, wid = tid >> 6;
    unsigned inc = lc;
    for (int off = 1; off < 64; off <<= 1) {
        unsigned o = __shfl_up(inc, off, 64);
        if (lane >= (unsigned)off) inc += o;
    }
    if (lane == 63) swsum[wid] = inc;
    __syncthreads();
    if (tid == 0) {
        unsigned run = 0;
        for (int w = 0; w < NT / 64; ++w) { unsigned t = swsum[w]; swsum[w] = run; run += t; }
        s_nk = run;
    }
    __syncthreads();
    unsigned bse = swsum[wid] + (inc - lc);
    for (int c2 = 0; c2 < EPT; ++c2) {
        if (kflag[c2]) {
            if (bse < MAXP) ssel[bse] = ordj[c2];
            ++bse;
        }
    }
    const unsigned nk_pre = s_nk;
    __syncthreads();

    if (tid < MAXP) {
        if (nk_pre == 0) {
            ssel[tid] = ~(unsigned)skeys[NN - 1];
        } else if (tid >= nk_pre) {
            ssel[tid] = ssel[nk_pre - 1];
        }
    }
    __syncthreads();

    if (tid < MAXP) {
        unsigned si = ssel[tid];
        const float* P = Pb + (size_t)si * 4;
        float* ob = out + ((size_t)b * MAXP + tid) * 4;
        ob[0] = P[0]; ob[1] = P[1]; ob[2] = P[2]; ob[3] = P[3];
        out[(size_t)BB * MAXP * 4 + (size_t)b * MAXP + tid] = Cb[si * 2 + 1];
    }
}

extern "C" void kernel_launch(void* const* d_in, const int* in_sizes, int n_in,
                              void* d_out, int out_size, void* d_ws, size_t ws_size,
                              hipStream_t stream) {
    const float* proposals = (const float*)d_in[0];
    const float* cls = (const float*)d_in[1];
    float* out = (float*)d_out;

    const size_t MASK_BYTES = (size_t)BB * NN * WPR * sizeof(ull);      // 32 MB
    const size_t SOA = (size_t)BB * NN;
    const size_t need_sz = MASK_BYTES + SOA * sizeof(float4) + SOA * sizeof(float)
                         + SOA * sizeof(unsigned) + 256;

    if (ws_size < need_sz) {
        nms_fallback<<<BB, NT, 0, stream>>>(proposals, cls, out);
        return;
    }

    ull* mask = (ull*)d_ws;
    float4* wbox = (float4*)((char*)d_ws + MASK_BYTES);
    float* war = (float*)(wbox + SOA);
    unsigned* sord = (unsigned*)(war + SOA);
    unsigned* wnv = sord + SOA;
    unsigned* need = wnv + BB;

    fused_kernel<<<BB, NT, 0, stream>>>(proposals, cls, sord, wnv, need, out);
    // phase-2 (no-ops unless some image's 300th kept box lies beyond sorted row RTOP)
    scatter_kernel<<<BB, NT, 0, stream>>>(proposals, sord, need, wbox, war);
    mask_kernel<<<dim3(MBPI, BB), MBT, 0, stream>>>(wbox, war, wnv, need, mask);
    scan_out_kernel<<<BB, SNT, 0, stream>>>(proposals, cls, sord, wnv, need, mask, out);
}

// Round 7
// 112.124 us; speedup vs baseline: 14.7765x; 1.0313x over previous
//
#include <hip/hip_runtime.h>

typedef unsigned long long ull;

#define BB 16
#define NN 4096
#define NT 1024
#define EPT 4
#define MAXP 300
#define IOU_THRESH 0.7f
#define SCORE_THR 0.5f

#define FNT 256                 // filter/sort kernel threads
#define FEPT (NN / FNT)         // 16 elements per thread
#define CCAP 1024               // candidate capacity (sorted window source)
#define RTOP 512                // fast-path window
#define RW (RTOP / 64)          // 8 mask words per row

__device__ __forceinline__ bool iou_ge(float ix1, float iy1, float ix2, float iy2, float ia,
                                       float x1, float y1, float x2, float y2, float aj) {
    float xx1 = fmaxf(ix1, x1);
    float yy1 = fmaxf(iy1, y1);
    float xx2 = fminf(ix2, x2);
    float yy2 = fminf(iy2, y2);
    float iw = fmaxf(__fsub_rn(xx2, xx1), 0.0f);
    float ih = fmaxf(__fsub_rn(yy2, yy1), 0.0f);
    float inter = __fmul_rn(iw, ih);
    float uni = __fsub_rn(__fadd_rn(ia, aj), inter);
    float iou = __fdiv_rn(inter, uni);
    return iou >= IOU_THRESH;
}

// ============ Kernel 1: threshold-filter + compact + sort 1024 candidates ============
__global__ __launch_bounds__(FNT) void filter_sort_kernel(const float* __restrict__ cls,
                                                          unsigned* __restrict__ cidx,
                                                          unsigned* __restrict__ wnv,
                                                          unsigned* __restrict__ need0) {
    __shared__ ull ck[CCAP];                 // 8 KB
    __shared__ unsigned hist[256];
    __shared__ unsigned swsum[FNT / 64];
    __shared__ unsigned s_nv, s_t, s_abv, s_sz;

    const int b = blockIdx.x, tid = threadIdx.x;
    const unsigned lane = tid & 63, wv = tid >> 6;
    const float* Cb = cls + (size_t)b * NN * 2;

    hist[tid] = 0;
    for (int c = tid; c < CCAP; c += FNT) ck[c] = 0;
    if (tid == 0) s_nv = 0;
    __syncthreads();

    // ---- pass 1: valid count + level-1 histogram (bin1 = mb>>24, monotone) ----
    unsigned lv = 0;
    #pragma unroll
    for (int c = 0; c < FEPT; ++c) {
        int i = c * FNT + tid;
        float sc = Cb[2 * i + 1];
        if (sc > SCORE_THR) {
            unsigned mb = __float_as_uint(sc) | 0x80000000u;
            atomicAdd(&hist[mb >> 24], 1u);
            ++lv;
        }
    }
    for (int off = 32; off > 0; off >>= 1) lv += __shfl_down(lv, off, 64);
    if (lane == 0) atomicAdd(&s_nv, lv);
    __syncthreads();

    const unsigned nv = s_nv;
    const unsigned target = nv < (unsigned)RTOP ? nv : (unsigned)RTOP;

    // ---- wave 0: suffix-scan over bins, pick t1 = largest bin with suffix >= target ----
    if (tid < 64) {
        unsigned h[4], S[4], local = 0;
        #pragma unroll
        for (int c = 0; c < 4; ++c) { h[c] = hist[tid * 4 + c]; local += h[c]; }
        unsigned inc = local;
        for (int off = 1; off < 64; off <<= 1) {
            unsigned t = __shfl_down(inc, off, 64);
            if (tid + off < 64) inc += t;
        }
        unsigned above = inc - local;
        S[3] = above + h[3];
        S[2] = S[3] + h[2];
        S[1] = S[2] + h[1];
        S[0] = S[1] + h[0];
        int bestc = -1;
        #pragma unroll
        for (int c = 3; c >= 0; --c) if (bestc < 0 && S[c] >= target) bestc = c;
        ull m = __ballot(bestc >= 0);
        int L = 63 - __builtin_clzll(m);
        if (tid == L) {
            s_t = (unsigned)(tid * 4 + bestc);
            s_abv = S[bestc] - h[bestc];
            s_sz = h[bestc];
        }
    }
    __syncthreads();
    const unsigned t1 = s_t;
    const unsigned abv1 = s_abv;
    const int lvl2 = (s_abv + s_sz > CCAP);     // uniform
    unsigned t2 = 0, Ccand;

    if (lvl2) {
        // ---- level-2 histogram within bin t1 (bin2 = (mb>>16)&0xFF, monotone inside t1) ----
        hist[tid] = 0;
        __syncthreads();
        #pragma unroll
        for (int c = 0; c < FEPT; ++c) {
            int i = c * FNT + tid;
            float sc = Cb[2 * i + 1];
            if (sc > SCORE_THR) {
                unsigned mb = __float_as_uint(sc) | 0x80000000u;
                if ((mb >> 24) == t1) atomicAdd(&hist[(mb >> 16) & 0xFFu], 1u);
            }
        }
        __syncthreads();
        const unsigned target2 = target - abv1;
        if (tid < 64) {
            unsigned h[4], S[4], local = 0;
            #pragma unroll
            for (int c = 0; c < 4; ++c) { h[c] = hist[tid * 4 + c]; local += h[c]; }
            unsigned inc = local;
            for (int off = 1; off < 64; off <<= 1) {
                unsigned t = __shfl_down(inc, off, 64);
                if (tid + off < 64) inc += t;
            }
            unsigned above = inc - local;
            S[3] = above + h[3];
            S[2] = S[3] + h[2];
            S[1] = S[2] + h[1];
            S[0] = S[1] + h[0];
            int bestc = -1;
            #pragma unroll
            for (int c = 3; c >= 0; --c) if (bestc < 0 && S[c] >= target2) bestc = c;
            ull m = __ballot(bestc >= 0);
            int L = 63 - __builtin_clzll(m);
            if (tid == L) {
                s_t = (unsigned)(tid * 4 + bestc);
                s_abv = S[bestc] - h[bestc];
                s_sz = h[bestc];
            }
        }
        __syncthreads();
        t2 = s_t;
        Ccand = abv1 + s_abv + s_sz;
    } else {
        Ccand = s_abv + s_sz;
    }

    if (tid == 0) { need0[b] = (Ccand > CCAP) ? 1u : 0u; wnv[b] = nv; }

    // ---- compact candidates (predicate is a superset of the exact top-target) ----
    unsigned pf[FEPT];
    ull keys[FEPT];
    unsigned lc = 0;
    #pragma unroll
    for (int c = 0; c < FEPT; ++c) {
        int i = c * FNT + tid;
        float sc = Cb[2 * i + 1];
        unsigned p = 0; ull key = 0;
        if (sc > SCORE_THR) {
            unsigned mb = __float_as_uint(sc) | 0x80000000u;
            unsigned b1 = mb >> 24;
            if (b1 > t1 || (b1 == t1 && (!lvl2 || ((mb >> 16) & 0xFFu) >= t2))) {
                p = 1;
                key = ((ull)mb << 32) | (unsigned)(~i);
            }
        }
        pf[c] = p; keys[c] = key; lc += p;
    }
    unsigned inc = lc;
    for (int off = 1; off < 64; off <<= 1) {
        unsigned o = __shfl_up(inc, off, 64);
        if (lane >= (unsigned)off) inc += o;
    }
    if (lane == 63) swsum[wv] = inc;
    __syncthreads();
    if (tid == 0) {
        unsigned run = 0;
        for (int w = 0; w < FNT / 64; ++w) { unsigned t = swsum[w]; swsum[w] = run; run += t; }
    }
    __syncthreads();
    unsigned pos = swsum[wv] + (inc - lc);
    #pragma unroll
    for (int c = 0; c < FEPT; ++c) {
        if (pf[c]) {
            if (pos < CCAP) ck[pos] = keys[c];
            ++pos;
        }
    }
    __syncthreads();

    // ---- bitonic sort of CCAP keys (descending), pair-enumerated (validated formula) ----
    for (unsigned k = 2; k <= CCAP; k <<= 1) {
        for (unsigned j = k >> 1; j > 0; j >>= 1) {
            for (unsigned p = tid; p < CCAP / 2; p += FNT) {
                unsigned low = p & (j - 1);
                unsigned i2 = ((p ^ low) << 1) | low;
                unsigned ixj = i2 | j;
                ull a = ck[i2], c2 = ck[ixj];
                if ((a < c2) == ((i2 & k) == 0)) { ck[i2] = c2; ck[ixj] = a; }
            }
            __syncthreads();
        }
    }

    // ---- emit sorted top-512 original indices ----
    cidx[(size_t)b * RTOP + tid] = ~(unsigned)ck[tid];
    cidx[(size_t)b * RTOP + FNT + tid] = ~(unsigned)ck[FNT + tid];
}

// ============ Kernel 2: 512x512 LDS bit-matrix + greedy scan + output ============
__global__ __launch_bounds__(NT) void mask_scan_out_kernel(const float* __restrict__ proposals,
                                                           const float* __restrict__ cls,
                                                           const unsigned* __restrict__ cidx,
                                                           const unsigned* __restrict__ wnv,
                                                           const unsigned* __restrict__ need0,
                                                           unsigned* __restrict__ need1,
                                                           float* __restrict__ out) {
    __shared__ ull smask[RTOP][RW];          // 32 KB
    __shared__ float sx1[RTOP], sy1[RTOP], sx2[RTOP], sy2[RTOP], sar[RTOP];  // 10 KB
    __shared__ unsigned soi[RTOP];
    __shared__ unsigned ssel[MAXP];
    __shared__ unsigned s_nk;

    const int b = blockIdx.x, tid = threadIdx.x;
    const unsigned nv = wnv[b];
    const unsigned R2 = nv < (unsigned)RTOP ? nv : (unsigned)RTOP;
    const float4* Pb4 = (const float4*)(proposals + (size_t)b * NN * 4);
    const float* Cb = cls + (size_t)b * NN * 2;

    if (tid < RTOP) {
        if ((unsigned)tid < R2) {
            unsigned oi = cidx[(size_t)b * RTOP + tid];
            soi[tid] = oi;
            float4 v = Pb4[oi];
            sx1[tid] = v.x; sy1[tid] = v.y; sx2[tid] = v.z; sy2[tid] = v.w;
            sar[tid] = __fmul_rn(__fsub_rn(v.z, v.x), __fsub_rn(v.w, v.y));
        } else {
            soi[tid] = 0;
            sx1[tid] = 0.f; sy1[tid] = 0.f; sx2[tid] = 0.f; sy2[tid] = 0.f;
            sar[tid] = 0.f;
        }
    }
    __syncthreads();

    // ---- mask-gen ----
    {
        const unsigned lane = tid & 63, wave = tid >> 6;
        const unsigned wlastR = R2 ? (R2 - 1) >> 6 : 0;
        for (unsigned i = wave; i < R2; i += NT / 64) {
            float ix1 = sx1[i], iy1 = sy1[i], ix2 = sx2[i], iy2 = sy2[i], ia = sar[i];
            const unsigned w0 = i >> 6;
            ull my = 0;
            for (unsigned w = w0; w <= wlastR; ++w) {
                unsigned jj = (w << 6) | lane;
                bool pred = (jj > i) && iou_ge(ix1, iy1, ix2, iy2, ia,
                                               sx1[jj], sy1[jj], sx2[jj], sy2[jj], sar[jj]);
                ull bal = __ballot(pred);
                if (lane == w) my = bal;
            }
            if (lane >= w0 && lane < RW) smask[i][lane] = my;
        }
    }
    __syncthreads();

    // ---- greedy OR-scan (wave 0), early-exit at MAXP ----
    if (tid < 64) {
        const unsigned lane = tid;
        unsigned lb = lane << 6;
        ull sup;
        if (lb >= nv) sup = ~0ULL;
        else if (lb + 64 <= nv) sup = 0ULL;
        else sup = (~0ULL) << (nv - lb);

        unsigned cnt = 0;
        if (R2 > 0) {
            auto ldrow = [&](unsigned g) -> ull {
                unsigned rr = g * 8 + (lane >> 3);
                if (rr >= RTOP) rr = 0;
                return smask[rr][lane & 7];
            };
            const unsigned ng = (R2 + 7) >> 3;
            ull bufA = ldrow(0), bufB = 0;
            for (unsigned g = 0; g < ng && cnt < MAXP; ++g) {
                if (g + 1 < ng) bufB = ldrow(g + 1);
                #pragma unroll
                for (int k2 = 0; k2 < 8; ++k2) {
                    unsigned i = g * 8 + (unsigned)k2;
                    if (i >= R2) break;                          // wave-uniform
                    bool kb = (lane == (i >> 6)) && (((sup >> (i & 63)) & 1ULL) == 0ULL);
                    ull km = __ballot(kb);
                    if (km) {                                     // wave-uniform
                        if (lane == 0) ssel[cnt] = i;
                        ++cnt;
                        ull rw = __shfl(bufA, (int)(((i & 7) << 3) | (lane & 7)), 64);
                        if (lane >= (i >> 6) && lane < RW) sup |= rw;
                        if (cnt == MAXP) break;
                    }
                }
                bufA = bufB;
            }
        }
        if (lane == 0) {
            s_nk = cnt;
            need1[b] = need0[b] | ((cnt < MAXP && nv > (unsigned)RTOP) ? 1u : 0u);
        }
    }
    __syncthreads();

    // ---- output (overwritten by guarded fallback when need1) ----
    const unsigned nk = s_nk;
    if (tid < MAXP) {
        unsigned p = (nk == 0) ? (NN - 1) : ssel[tid < nk ? tid : nk - 1];
        unsigned oi; float x1, y1, x2, y2;
        if (p < RTOP) {
            oi = soi[p];
            x1 = sx1[p]; y1 = sy1[p]; x2 = sx2[p]; y2 = sy2[p];
        } else {
            oi = NN - 1;                        // only reachable when nk==0 (nv==0)
            float4 v = Pb4[oi];
            x1 = v.x; y1 = v.y; x2 = v.z; y2 = v.w;
        }
        float sc = Cb[oi * 2 + 1];
        float* ob = out + ((size_t)b * MAXP + tid) * 4;
        ob[0] = x1; ob[1] = y1; ob[2] = x2; ob[3] = y2;
        out[(size_t)BB * MAXP * 4 + (size_t)b * MAXP + tid] = sc;
    }
}

// ============ Guarded full fallback (round-2 monolithic, validated) ============
#define CH 64
#define TPC (CH / EPT)
__global__ __launch_bounds__(NT) void nms_fallback(const float* __restrict__ proposals,
                                                   const float* __restrict__ cls,
                                                   const unsigned* __restrict__ need1,
                                                   float* __restrict__ out) {
    __shared__ unsigned long long skeys[NN];
    __shared__ unsigned char ssup[NN];
    __shared__ float cbx1[2][CH], cby1[2][CH], cbx2[2][CH], cby2[2][CH], cbar[2][CH];
    __shared__ unsigned long long skept[2];
    __shared__ unsigned int ssel[MAXP];
    __shared__ unsigned int swsum[NT / 64];
    __shared__ unsigned int s_nvalid;
    __shared__ unsigned int s_nk;

    const int b = blockIdx.x;
    if (need1 && !need1[b]) return;
    const int tid = threadIdx.x;
    const float* Pb = proposals + (size_t)b * NN * 4;
    const float* Cb = cls + (size_t)b * NN * 2;

    if (tid == 0) s_nvalid = 0;
    __syncthreads();

    unsigned lv = 0;
    for (int i = tid; i < NN; i += NT) {
        float sc = Cb[i * 2 + 1];
        bool valid = sc > SCORE_THR;
        unsigned mb = valid ? (__float_as_uint(sc) | 0x80000000u) : 0u;
        skeys[i] = ((unsigned long long)mb << 32) | (unsigned)(~i);
        lv += valid ? 1u : 0u;
    }
    for (int off = 32; off > 0; off >>= 1) lv += __shfl_down(lv, off, 64);
    if ((tid & 63) == 0) atomicAdd(&s_nvalid, lv);

    for (unsigned k = 2; k <= NN; k <<= 1) {
        for (unsigned j = k >> 1; j > 0; j >>= 1) {
            __syncthreads();
            for (unsigned p = tid; p < NN / 2; p += NT) {
                unsigned low = p & (j - 1);
                unsigned i = ((p ^ low) << 1) | low;
                unsigned ixj = i | j;
                unsigned long long a = skeys[i], c = skeys[ixj];
                if ((a < c) == ((i & k) == 0)) { skeys[i] = c; skeys[ixj] = a; }
            }
        }
    }
    __syncthreads();

    const unsigned n_valid = s_nvalid;

    unsigned ordj[EPT];
    float bx1[EPT], by1[EPT], bx2[EPT], by2[EPT], bar[EPT];
    int rflag[EPT];
    for (int c2 = 0; c2 < EPT; ++c2) {
        int j = tid * EPT + c2;
        unsigned oi = ~(unsigned)skeys[j];
        ordj[c2] = oi;
        const float* P = Pb + (size_t)oi * 4;
        float x1 = P[0], y1 = P[1], x2 = P[2], y2 = P[3];
        bx1[c2] = x1; by1[c2] = y1; bx2[c2] = x2; by2[c2] = y2;
        bar[c2] = __fmul_rn(__fsub_rn(x2, x1), __fsub_rn(y2, y1));
        int sup = (j < (int)n_valid) ? 0 : 1;
        rflag[c2] = sup;
        ssup[j] = (unsigned char)sup;
    }

    const unsigned nch = (n_valid + CH - 1) / CH;
    for (unsigned c = 0; c < nch; ++c) {
        const int p = (int)(c & 1);
        if (tid >= (int)(TPC * c) && tid < (int)(TPC * (c + 1))) {
            int bse = (tid - TPC * c) * EPT;
            #pragma unroll
            for (int c2 = 0; c2 < EPT; ++c2) {
                int l = bse + c2;
                cbx1[p][l] = bx1[c2]; cby1[p][l] = by1[c2];
                cbx2[p][l] = bx2[c2]; cby2[p][l] = by2[c2];
                cbar[p][l] = bar[c2];
            }
        }
        __syncthreads();

        if (tid < CH) {
            const int l = tid;
            const int j = (int)(c * CH) + l;
            float x1 = cbx1[p][l], y1 = cby1[p][l], x2 = cbx2[p][l], y2 = cby2[p][l];
            float ar = cbar[p][l];
            int supl = ssup[j];
            unsigned long long row = 0ULL;
            for (int m = l + 1; m < CH; ++m) {
                bool s = iou_ge(x1, y1, x2, y2, ar,
                                cbx1[p][m], cby1[p][m], cbx2[p][m], cby2[p][m], cbar[p][m]);
                if (s) row |= (1ULL << m);
            }
            unsigned long long S = __ballot(supl != 0);
            for (int i = 0; i < CH; ++i) {
                unsigned long long ri = __shfl(row, i, 64);
                if (!((S >> i) & 1ULL)) S |= ri;
            }
            ssup[j] = (unsigned char)((S >> l) & 1ULL);
            if (l == 0) skept[p] = ~S;
        }
        __syncthreads();

        const int myFirst = tid * EPT;
        if (myFirst >= (int)(CH * (c + 1)) &&
            !(rflag[0] & rflag[1] & rflag[2] & rflag[3])) {
            unsigned long long K = skept[p];
            while (K) {
                int m = __builtin_ctzll(K);
                K &= K - 1;
                float mx1 = cbx1[p][m], my1 = cby1[p][m];
                float mx2 = cbx2[p][m], my2 = cby2[p][m];
                float ma = cbar[p][m];
                #pragma unroll
                for (int c2 = 0; c2 < EPT; ++c2) {
                    if (!rflag[c2]) {
                        bool s = iou_ge(mx1, my1, mx2, my2, ma,
                                        bx1[c2], by1[c2], bx2[c2], by2[c2], bar[c2]);
                        if (s) { rflag[c2] = 1; ssup[myFirst + c2] = 1; }
                    }
                }
            }
        }
    }
    __syncthreads();

    unsigned kflag[EPT];
    unsigned lc = 0;
    for (int c2 = 0; c2 < EPT; ++c2) {
        int j = tid * EPT + c2;
        kflag[c2] = ssup[j] ? 0u : 1u;
        lc += kflag[c2];
    }
    unsigned lane = tid & 63, wid = tid >> 6;
    unsigned inc = lc;
    for (int off = 1; off < 64; off <<= 1) {
        unsigned o = __shfl_up(inc, off, 64);
        if (lane >= (unsigned)off) inc += o;
    }
    if (lane == 63) swsum[wid] = inc;
    __syncthreads();
    if (tid == 0) {
        unsigned run = 0;
        for (int w = 0; w < NT / 64; ++w) { unsigned t = swsum[w]; swsum[w] = run; run += t; }
        s_nk = run;
    }
    __syncthreads();
    unsigned bse = swsum[wid] + (inc - lc);
    for (int c2 = 0; c2 < EPT; ++c2) {
        if (kflag[c2]) {
            if (bse < MAXP) ssel[bse] = ordj[c2];
            ++bse;
        }
    }
    const unsigned nk_pre = s_nk;
    __syncthreads();

    if (tid < MAXP) {
        if (nk_pre == 0) {
            ssel[tid] = ~(unsigned)skeys[NN - 1];
        } else if (tid >= nk_pre) {
            ssel[tid] = ssel[nk_pre - 1];
        }
    }
    __syncthreads();

    if (tid < MAXP) {
        unsigned si = ssel[tid];
        const float* P = Pb + (size_t)si * 4;
        float* ob = out + ((size_t)b * MAXP + tid) * 4;
        ob[0] = P[0]; ob[1] = P[1]; ob[2] = P[2]; ob[3] = P[3];
        out[(size_t)BB * MAXP * 4 + (size_t)b * MAXP + tid] = Cb[si * 2 + 1];
    }
}

extern "C" void kernel_launch(void* const* d_in, const int* in_sizes, int n_in,
                              void* d_out, int out_size, void* d_ws, size_t ws_size,
                              hipStream_t stream) {
    const float* proposals = (const float*)d_in[0];
    const float* cls = (const float*)d_in[1];
    float* out = (float*)d_out;

    const size_t need_sz = (size_t)BB * RTOP * sizeof(unsigned) + 3 * BB * sizeof(unsigned) + 256;
    if (ws_size < need_sz) {
        nms_fallback<<<BB, NT, 0, stream>>>(proposals, cls, (const unsigned*)nullptr, out);
        return;
    }

    unsigned* cidx = (unsigned*)d_ws;                 // BB * 512
    unsigned* wnv = cidx + (size_t)BB * RTOP;         // BB
    unsigned* need0 = wnv + BB;                       // BB
    unsigned* need1 = need0 + BB;                     // BB

    filter_sort_kernel<<<BB, FNT, 0, stream>>>(cls, cidx, wnv, need0);
    mask_scan_out_kernel<<<BB, NT, 0, stream>>>(proposals, cls, cidx, wnv, need0, need1, out);
    nms_fallback<<<BB, NT, 0, stream>>>(proposals, cls, need1, out);   // no-op unless flagged
}

// Round 8
// 85.414 us; speedup vs baseline: 19.3974x; 1.3127x over previous
//
#include <hip/hip_runtime.h>

typedef unsigned long long ull;

#define BB 16
#define NN 4096
#define NT 1024
#define EPT 4
#define MAXP 300
#define IOU_THRESH 0.7f
#define SCORE_THR 0.5f

#define FNT 512                 // filter/sort kernel threads
#define FEPT (NN / FNT)         // 8 elements per thread
#define CCAP 1024               // candidate capacity
#define RTOP 512                // fast-path window
#define RW (RTOP / 64)          // 8 mask words per row
#define PD 16                   // scan prefetch depth

__device__ __forceinline__ bool iou_ge(float ix1, float iy1, float ix2, float iy2, float ia,
                                       float x1, float y1, float x2, float y2, float aj) {
    float xx1 = fmaxf(ix1, x1);
    float yy1 = fmaxf(iy1, y1);
    float xx2 = fminf(ix2, x2);
    float yy2 = fminf(iy2, y2);
    float iw = fmaxf(__fsub_rn(xx2, xx1), 0.0f);
    float ih = fmaxf(__fsub_rn(yy2, yy1), 0.0f);
    float inter = __fmul_rn(iw, ih);
    float uni = __fsub_rn(__fadd_rn(ia, aj), inter);
    float iou = __fdiv_rn(inter, uni);
    return iou >= IOU_THRESH;
}

// ============ K1: threshold-filter + compact + sort + SoA emit ============
__global__ __launch_bounds__(FNT, 1) void filter_sort_kernel(const float* __restrict__ proposals,
                                                             const float* __restrict__ cls,
                                                             float* __restrict__ wx1, float* __restrict__ wy1,
                                                             float* __restrict__ wx2, float* __restrict__ wy2,
                                                             float* __restrict__ war,
                                                             unsigned* __restrict__ cidx,
                                                             unsigned* __restrict__ wnv,
                                                             unsigned* __restrict__ need0) {
    __shared__ ull ck[CCAP];                 // 8 KB
    __shared__ unsigned hist[256];
    __shared__ unsigned swsum[FNT / 64];
    __shared__ unsigned s_nv, s_t, s_abv, s_sz;

    const int b = blockIdx.x, tid = threadIdx.x;
    const unsigned lane = tid & 63, wv = tid >> 6;
    const float* Cb = cls + (size_t)b * NN * 2;
    const float4* Pb4 = (const float4*)(proposals + (size_t)b * NN * 4);

    if (tid < 256) hist[tid] = 0;
    ck[tid] = 0; ck[tid + FNT] = 0;
    if (tid == 0) s_nv = 0;
    __syncthreads();

    // ---- pass 1: valid count + level-1 histogram (bin1 = mb>>24, monotone) ----
    unsigned lv = 0;
    #pragma unroll
    for (int c = 0; c < FEPT; ++c) {
        int i = c * FNT + tid;
        float sc = Cb[2 * i + 1];
        if (sc > SCORE_THR) {
            unsigned mb = __float_as_uint(sc) | 0x80000000u;
            atomicAdd(&hist[mb >> 24], 1u);
            ++lv;
        }
    }
    for (int off = 32; off > 0; off >>= 1) lv += __shfl_down(lv, off, 64);
    if (lane == 0) atomicAdd(&s_nv, lv);
    __syncthreads();

    const unsigned nv = s_nv;
    const unsigned target = nv < (unsigned)RTOP ? nv : (unsigned)RTOP;

    // ---- wave 0: suffix-scan over bins, pick t1 ----
    if (tid < 64) {
        unsigned h[4], S[4], local = 0;
        #pragma unroll
        for (int c = 0; c < 4; ++c) { h[c] = hist[tid * 4 + c]; local += h[c]; }
        unsigned inc = local;
        for (int off = 1; off < 64; off <<= 1) {
            unsigned t = __shfl_down(inc, off, 64);
            if (tid + off < 64) inc += t;
        }
        unsigned above = inc - local;
        S[3] = above + h[3];
        S[2] = S[3] + h[2];
        S[1] = S[2] + h[1];
        S[0] = S[1] + h[0];
        int bestc = -1;
        #pragma unroll
        for (int c = 3; c >= 0; --c) if (bestc < 0 && S[c] >= target) bestc = c;
        ull m = __ballot(bestc >= 0);
        int L = 63 - __builtin_clzll(m);
        if (tid == L) {
            s_t = (unsigned)(tid * 4 + bestc);
            s_abv = S[bestc] - h[bestc];
            s_sz = h[bestc];
        }
    }
    __syncthreads();
    const unsigned t1 = s_t;
    const unsigned abv1 = s_abv;
    const int lvl2 = (s_abv + s_sz > CCAP);     // uniform
    unsigned t2 = 0, Ccand;

    if (lvl2) {
        if (tid < 256) hist[tid] = 0;
        __syncthreads();
        #pragma unroll
        for (int c = 0; c < FEPT; ++c) {
            int i = c * FNT + tid;
            float sc = Cb[2 * i + 1];
            if (sc > SCORE_THR) {
                unsigned mb = __float_as_uint(sc) | 0x80000000u;
                if ((mb >> 24) == t1) atomicAdd(&hist[(mb >> 16) & 0xFFu], 1u);
            }
        }
        __syncthreads();
        const unsigned target2 = target - abv1;
        if (tid < 64) {
            unsigned h[4], S[4], local = 0;
            #pragma unroll
            for (int c = 0; c < 4; ++c) { h[c] = hist[tid * 4 + c]; local += h[c]; }
            unsigned inc = local;
            for (int off = 1; off < 64; off <<= 1) {
                unsigned t = __shfl_down(inc, off, 64);
                if (tid + off < 64) inc += t;
            }
            unsigned above = inc - local;
            S[3] = above + h[3];
            S[2] = S[3] + h[2];
            S[1] = S[2] + h[1];
            S[0] = S[1] + h[0];
            int bestc = -1;
            #pragma unroll
            for (int c = 3; c >= 0; --c) if (bestc < 0 && S[c] >= target2) bestc = c;
            ull m = __ballot(bestc >= 0);
            int L = 63 - __builtin_clzll(m);
            if (tid == L) {
                s_t = (unsigned)(tid * 4 + bestc);
                s_abv = S[bestc] - h[bestc];
                s_sz = h[bestc];
            }
        }
        __syncthreads();
        t2 = s_t;
        Ccand = abv1 + s_abv + s_sz;
    } else {
        Ccand = s_abv + s_sz;
    }

    if (tid == 0) { need0[b] = (Ccand > CCAP) ? 1u : 0u; wnv[b] = nv; }

    // ---- compact candidates (superset of exact top-target) ----
    unsigned pf[FEPT];
    ull keys[FEPT];
    unsigned lc = 0;
    #pragma unroll
    for (int c = 0; c < FEPT; ++c) {
        int i = c * FNT + tid;
        float sc = Cb[2 * i + 1];
        unsigned p = 0; ull key = 0;
        if (sc > SCORE_THR) {
            unsigned mb = __float_as_uint(sc) | 0x80000000u;
            unsigned b1 = mb >> 24;
            if (b1 > t1 || (b1 == t1 && (!lvl2 || ((mb >> 16) & 0xFFu) >= t2))) {
                p = 1;
                key = ((ull)mb << 32) | (unsigned)(~i);
            }
        }
        pf[c] = p; keys[c] = key; lc += p;
    }
    unsigned inc = lc;
    for (int off = 1; off < 64; off <<= 1) {
        unsigned o = __shfl_up(inc, off, 64);
        if (lane >= (unsigned)off) inc += o;
    }
    if (lane == 63) swsum[wv] = inc;
    __syncthreads();
    if (tid == 0) {
        unsigned run = 0;
        for (int w = 0; w < FNT / 64; ++w) { unsigned t = swsum[w]; swsum[w] = run; run += t; }
    }
    __syncthreads();
    unsigned pos = swsum[wv] + (inc - lc);
    #pragma unroll
    for (int c = 0; c < FEPT; ++c) {
        if (pf[c]) {
            if (pos < CCAP) ck[pos] = keys[c];
            ++pos;
        }
    }
    __syncthreads();

    // ---- bitonic sort of CCAP keys (descending), pair-enumerated ----
    for (unsigned k = 2; k <= CCAP; k <<= 1) {
        for (unsigned j = k >> 1; j > 0; j >>= 1) {
            unsigned p = tid;                     // exactly CCAP/2 pairs = FNT threads
            unsigned low = p & (j - 1);
            unsigned i2 = ((p ^ low) << 1) | low;
            unsigned ixj = i2 | j;
            ull a = ck[i2], c2 = ck[ixj];
            if ((a < c2) == ((i2 & k) == 0)) { ck[i2] = c2; ck[ixj] = a; }
            __syncthreads();
        }
    }

    // ---- emit sorted top-512: SoA boxes + area + original index ----
    if (tid < RTOP) {
        const size_t base = (size_t)b * RTOP;
        ull key = ck[tid];
        unsigned oi = key ? ~(unsigned)key : 0u;
        float4 v = make_float4(0.f, 0.f, 0.f, 0.f);
        if (key) v = Pb4[oi];
        wx1[base + tid] = v.x; wy1[base + tid] = v.y;
        wx2[base + tid] = v.z; wy2[base + tid] = v.w;
        war[base + tid] = __fmul_rn(__fsub_rn(v.z, v.x), __fsub_rn(v.w, v.y));
        cidx[base + tid] = oi;
    }
}

// ============ K2: 512x512 suppression bit-matrix -> global (parallel) ============
__global__ __launch_bounds__(256) void mask512_kernel(const float* __restrict__ wx1, const float* __restrict__ wy1,
                                                      const float* __restrict__ wx2, const float* __restrict__ wy2,
                                                      const float* __restrict__ war,
                                                      const unsigned* __restrict__ wnv,
                                                      ull* __restrict__ m8) {
    __shared__ float sx1[RTOP], sy1[RTOP], sx2[RTOP], sy2[RTOP], sar[RTOP];  // 10 KB
    const int img = blockIdx.y;
    const unsigned nv = wnv[img];
    const unsigned R2 = nv < (unsigned)RTOP ? nv : (unsigned)RTOP;
    if (R2 == 0) return;
    const int tid = threadIdx.x;
    const size_t base = (size_t)img * RTOP;

    for (int idx = tid; idx < RTOP; idx += 256) {
        sx1[idx] = wx1[base + idx];
        sy1[idx] = wy1[base + idx];
        sx2[idx] = wx2[base + idx];
        sy2[idx] = wy2[base + idx];
        sar[idx] = war[base + idx];
    }
    __syncthreads();

    const unsigned lane = tid & 63;
    const unsigned wvimg = blockIdx.x * 4 + (tid >> 6);   // 0..31 per image
    const unsigned wlastR = (R2 - 1) >> 6;
    ull* mimg = m8 + base * RW;

    for (unsigned i = wvimg; i < R2; i += 32) {           // interleaved: balances triangle
        float ix1 = sx1[i], iy1 = sy1[i], ix2 = sx2[i], iy2 = sy2[i], ia = sar[i];
        const unsigned w0 = i >> 6;
        ull my = 0;
        for (unsigned w = w0; w <= wlastR; ++w) {
            unsigned jj = (w << 6) | lane;
            bool pred = (jj > i) && iou_ge(ix1, iy1, ix2, iy2, ia,
                                           sx1[jj], sy1[jj], sx2[jj], sy2[jj], sar[jj]);
            ull bal = __ballot(pred);
            if (lane == w) my = bal;
        }
        if (lane < RW) {
            ull val = (lane >= w0 && lane <= wlastR) ? my : 0ULL;
            mimg[(size_t)i * RW + lane] = val;            // all 8 words defined
        }
    }
}

// ============ K3: serial greedy OR-scan (1 wave, big reg budget) + output ============
__global__ __launch_bounds__(64, 1) void scan_out_kernel(const float* __restrict__ proposals,
                                                         const float* __restrict__ cls,
                                                         const float* __restrict__ wx1, const float* __restrict__ wy1,
                                                         const float* __restrict__ wx2, const float* __restrict__ wy2,
                                                         const unsigned* __restrict__ cidx,
                                                         const unsigned* __restrict__ wnv,
                                                         const unsigned* __restrict__ need0,
                                                         unsigned* __restrict__ need1,
                                                         const ull* __restrict__ m8,
                                                         float* __restrict__ out) {
    __shared__ unsigned ssel[MAXP];
    const int b = blockIdx.x;
    const unsigned lane = threadIdx.x;                    // 0..63, one wave
    const unsigned nv = wnv[b];
    const unsigned R2 = nv < (unsigned)RTOP ? nv : (unsigned)RTOP;
    const size_t base = (size_t)b * RTOP;
    const float* Cb = cls + (size_t)b * NN * 2;
    const float4* Pb4 = (const float4*)(proposals + (size_t)b * NN * 4);

    ull sup;
    {
        unsigned lb = lane << 6;
        if (lane >= RW || lb >= nv) sup = ~0ULL;
        else if (lb + 64 <= nv) sup = 0ULL;
        else sup = (~0ULL) << (nv - lb);
    }

    unsigned cnt = 0;
    if (R2 > 0) {
        const ull* mimg = m8 + base * RW;
        const unsigned wsel = lane & (RW - 1);
        ull bufA[PD], bufB[PD];
        const unsigned ng = (R2 + PD - 1) / PD;

        // prefetch group 0
        #pragma unroll
        for (int k = 0; k < PD; ++k) {
            unsigned r = k; if (r >= RTOP) r = RTOP - 1;
            bufA[k] = mimg[(size_t)r * RW + wsel];
        }
        unsigned g = 0;
        while (true) {
            if (g + 1 < ng) {
                unsigned rb = (g + 1) * PD;
                #pragma unroll
                for (int k = 0; k < PD; ++k) {
                    unsigned r = rb + k; if (r >= RTOP) r = RTOP - 1;
                    bufB[k] = mimg[(size_t)r * RW + wsel];
                }
            }
            {
                bool done = false;
                #pragma unroll
                for (int k = 0; k < PD; ++k) {
                    unsigned i = g * PD + (unsigned)k;
                    if (i >= R2) { done = true; break; }
                    bool kb = (lane == (i >> 6)) && (((sup >> (i & 63)) & 1ULL) == 0ULL);
                    ull km = __ballot(kb);
                    if (km) {                              // wave-uniform
                        if (lane == 0) ssel[cnt] = i;
                        ++cnt;
                        sup |= bufA[k];                    // all 8 words defined; lanes>=8 junk-safe
                        if (cnt == MAXP) { done = true; break; }
                    }
                }
                if (done && (cnt == MAXP || g * PD + PD > R2)) break;
            }
            if (++g >= ng) break;
            if (g + 1 < ng) {
                unsigned rb = (g + 1) * PD;
                #pragma unroll
                for (int k = 0; k < PD; ++k) {
                    unsigned r = rb + k; if (r >= RTOP) r = RTOP - 1;
                    bufA[k] = mimg[(size_t)r * RW + wsel];
                }
            }
            {
                bool done = false;
                #pragma unroll
                for (int k = 0; k < PD; ++k) {
                    unsigned i = g * PD + (unsigned)k;
                    if (i >= R2) { done = true; break; }
                    bool kb = (lane == (i >> 6)) && (((sup >> (i & 63)) & 1ULL) == 0ULL);
                    ull km = __ballot(kb);
                    if (km) {
                        if (lane == 0) ssel[cnt] = i;
                        ++cnt;
                        sup |= bufB[k];
                        if (cnt == MAXP) { done = true; break; }
                    }
                }
                if (done && (cnt == MAXP || g * PD + PD > R2)) break;
            }
            if (++g >= ng) break;
        }
    }

    if (lane == 0)
        need1[b] = need0[b] | ((cnt < MAXP && nv > (unsigned)RTOP) ? 1u : 0u);

    // ---- output (cnt is wave-uniform; ssel LDS writes ordered within the wave) ----
    for (unsigned t = lane; t < MAXP; t += 64) {
        float x1, y1, x2, y2; unsigned oi;
        if (cnt == 0) {
            oi = NN - 1;
            float4 v = Pb4[oi];
            x1 = v.x; y1 = v.y; x2 = v.z; y2 = v.w;
        } else {
            unsigned p = ssel[t < cnt ? t : cnt - 1];
            oi = cidx[base + p];
            x1 = wx1[base + p]; y1 = wy1[base + p];
            x2 = wx2[base + p]; y2 = wy2[base + p];
        }
        float sc = Cb[2 * oi + 1];
        float* ob = out + ((size_t)b * MAXP + t) * 4;
        ob[0] = x1; ob[1] = y1; ob[2] = x2; ob[3] = y2;
        out[(size_t)BB * MAXP * 4 + (size_t)b * MAXP + t] = sc;
    }
}

// ============ Guarded full fallback (round-2 monolithic, validated) ============
#define CH 64
#define TPC (CH / EPT)
__global__ __launch_bounds__(NT) void nms_fallback(const float* __restrict__ proposals,
                                                   const float* __restrict__ cls,
                                                   const unsigned* __restrict__ need1,
                                                   float* __restrict__ out) {
    __shared__ unsigned long long skeys[NN];
    __shared__ unsigned char ssup[NN];
    __shared__ float cbx1[2][CH], cby1[2][CH], cbx2[2][CH], cby2[2][CH], cbar[2][CH];
    __shared__ unsigned long long skept[2];
    __shared__ unsigned int ssel[MAXP];
    __shared__ unsigned int swsum[NT / 64];
    __shared__ unsigned int s_nvalid;
    __shared__ unsigned int s_nk;

    const int b = blockIdx.x;
    if (need1 && !need1[b]) return;
    const int tid = threadIdx.x;
    const float* Pb = proposals + (size_t)b * NN * 4;
    const float* Cb = cls + (size_t)b * NN * 2;

    if (tid == 0) s_nvalid = 0;
    __syncthreads();

    unsigned lv = 0;
    for (int i = tid; i < NN; i += NT) {
        float sc = Cb[i * 2 + 1];
        bool valid = sc > SCORE_THR;
        unsigned mb = valid ? (__float_as_uint(sc) | 0x80000000u) : 0u;
        skeys[i] = ((unsigned long long)mb << 32) | (unsigned)(~i);
        lv += valid ? 1u : 0u;
    }
    for (int off = 32; off > 0; off >>= 1) lv += __shfl_down(lv, off, 64);
    if ((tid & 63) == 0) atomicAdd(&s_nvalid, lv);

    for (unsigned k = 2; k <= NN; k <<= 1) {
        for (unsigned j = k >> 1; j > 0; j >>= 1) {
            __syncthreads();
            for (unsigned p = tid; p < NN / 2; p += NT) {
                unsigned low = p & (j - 1);
                unsigned i = ((p ^ low) << 1) | low;
                unsigned ixj = i | j;
                unsigned long long a = skeys[i], c = skeys[ixj];
                if ((a < c) == ((i & k) == 0)) { skeys[i] = c; skeys[ixj] = a; }
            }
        }
    }
    __syncthreads();

    const unsigned n_valid = s_nvalid;

    unsigned ordj[EPT];
    float bx1[EPT], by1[EPT], bx2[EPT], by2[EPT], bar[EPT];
    int rflag[EPT];
    for (int c2 = 0; c2 < EPT; ++c2) {
        int j = tid * EPT + c2;
        unsigned oi = ~(unsigned)skeys[j];
        ordj[c2] = oi;
        const float* P = Pb + (size_t)oi * 4;
        float x1 = P[0], y1 = P[1], x2 = P[2], y2 = P[3];
        bx1[c2] = x1; by1[c2] = y1; bx2[c2] = x2; by2[c2] = y2;
        bar[c2] = __fmul_rn(__fsub_rn(x2, x1), __fsub_rn(y2, y1));
        int sup = (j < (int)n_valid) ? 0 : 1;
        rflag[c2] = sup;
        ssup[j] = (unsigned char)sup;
    }

    const unsigned nch = (n_valid + CH - 1) / CH;
    for (unsigned c = 0; c < nch; ++c) {
        const int p = (int)(c & 1);
        if (tid >= (int)(TPC * c) && tid < (int)(TPC * (c + 1))) {
            int bse = (tid - TPC * c) * EPT;
            #pragma unroll
            for (int c2 = 0; c2 < EPT; ++c2) {
                int l = bse + c2;
                cbx1[p][l] = bx1[c2]; cby1[p][l] = by1[c2];
                cbx2[p][l] = bx2[c2]; cby2[p][l] = by2[c2];
                cbar[p][l] = bar[c2];
            }
        }
        __syncthreads();

        if (tid < CH) {
            const int l = tid;
            const int j = (int)(c * CH) + l;
            float x1 = cbx1[p][l], y1 = cby1[p][l], x2 = cbx2[p][l], y2 = cby2[p][l];
            float ar = cbar[p][l];
            int supl = ssup[j];
            unsigned long long row = 0ULL;
            for (int m = l + 1; m < CH; ++m) {
                bool s = iou_ge(x1, y1, x2, y2, ar,
                                cbx1[p][m], cby1[p][m], cbx2[p][m], cby2[p][m], cbar[p][m]);
                if (s) row |= (1ULL << m);
            }
            unsigned long long S = __ballot(supl != 0);
            for (int i = 0; i < CH; ++i) {
                unsigned long long ri = __shfl(row, i, 64);
                if (!((S >> i) & 1ULL)) S |= ri;
            }
            ssup[j] = (unsigned char)((S >> l) & 1ULL);
            if (l == 0) skept[p] = ~S;
        }
        __syncthreads();

        const int myFirst = tid * EPT;
        if (myFirst >= (int)(CH * (c + 1)) &&
            !(rflag[0] & rflag[1] & rflag[2] & rflag[3])) {
            unsigned long long K = skept[p];
            while (K) {
                int m = __builtin_ctzll(K);
                K &= K - 1;
                float mx1 = cbx1[p][m], my1 = cby1[p][m];
                float mx2 = cbx2[p][m], my2 = cby2[p][m];
                float ma = cbar[p][m];
                #pragma unroll
                for (int c2 = 0; c2 < EPT; ++c2) {
                    if (!rflag[c2]) {
                        bool s = iou_ge(mx1, my1, mx2, my2, ma,
                                        bx1[c2], by1[c2], bx2[c2], by2[c2], bar[c2]);
                        if (s) { rflag[c2] = 1; ssup[myFirst + c2] = 1; }
                    }
                }
            }
        }
    }
    __syncthreads();

    unsigned kflag[EPT];
    unsigned lc = 0;
    for (int c2 = 0; c2 < EPT; ++c2) {
        int j = tid * EPT + c2;
        kflag[c2] = ssup[j] ? 0u : 1u;
        lc += kflag[c2];
    }
    unsigned lane = tid & 63, wid = tid >> 6;
    unsigned inc = lc;
    for (int off = 1; off < 64; off <<= 1) {
        unsigned o = __shfl_up(inc, off, 64);
        if (lane >= (unsigned)off) inc += o;
    }
    if (lane == 63) swsum[wid] = inc;
    __syncthreads();
    if (tid == 0) {
        unsigned run = 0;
        for (int w = 0; w < NT / 64; ++w) { unsigned t = swsum[w]; swsum[w] = run; run += t; }
        s_nk = run;
    }
    __syncthreads();
    unsigned bse = swsum[wid] + (inc - lc);
    for (int c2 = 0; c2 < EPT; ++c2) {
        if (kflag[c2]) {
            if (bse < MAXP) ssel[bse] = ordj[c2];
            ++bse;
        }
    }
    const unsigned nk_pre = s_nk;
    __syncthreads();

    if (tid < MAXP) {
        if (nk_pre == 0) {
            ssel[tid] = ~(unsigned)skeys[NN - 1];
        } else if (tid >= nk_pre) {
            ssel[tid] = ssel[nk_pre - 1];
        }
    }
    __syncthreads();

    if (tid < MAXP) {
        unsigned si = ssel[tid];
        const float* P = Pb + (size_t)si * 4;
        float* ob = out + ((size_t)b * MAXP + tid) * 4;
        ob[0] = P[0]; ob[1] = P[1]; ob[2] = P[2]; ob[3] = P[3];
        out[(size_t)BB * MAXP * 4 + (size_t)b * MAXP + tid] = Cb[si * 2 + 1];
    }
}

extern "C" void kernel_launch(void* const* d_in, const int* in_sizes, int n_in,
                              void* d_out, int out_size, void* d_ws, size_t ws_size,
                              hipStream_t stream) {
    const float* proposals = (const float*)d_in[0];
    const float* cls = (const float*)d_in[1];
    float* out = (float*)d_out;

    const size_t S = (size_t)BB * RTOP;
    const size_t need_sz = S * RW * sizeof(ull)       // m8
                         + S * 5 * sizeof(float)      // SoA
                         + S * sizeof(unsigned)       // cidx
                         + 3 * BB * sizeof(unsigned) + 256;
    if (ws_size < need_sz) {
        nms_fallback<<<BB, NT, 0, stream>>>(proposals, cls, (const unsigned*)nullptr, out);
        return;
    }

    ull* m8 = (ull*)d_ws;                             // 512 KB
    float* wx1 = (float*)(m8 + S * RW);
    float* wy1 = wx1 + S;
    float* wx2 = wy1 + S;
    float* wy2 = wx2 + S;
    float* war = wy2 + S;
    unsigned* cidx = (unsigned*)(war + S);
    unsigned* wnv = cidx + S;
    unsigned* need0 = wnv + BB;
    unsigned* need1 = need0 + BB;

    filter_sort_kernel<<<BB, FNT, 0, stream>>>(proposals, cls, wx1, wy1, wx2, wy2, war,
                                               cidx, wnv, need0);
    mask512_kernel<<<dim3(RTOP / 64, BB), 256, 0, stream>>>(wx1, wy1, wx2, wy2, war, wnv, m8);
    scan_out_kernel<<<BB, 64, 0, stream>>>(proposals, cls, wx1, wy1, wx2, wy2,
                                           cidx, wnv, need0, need1, m8, out);
    nms_fallback<<<BB, NT, 0, stream>>>(proposals, cls, need1, out);   // no-op unless flagged
}

// Round 9
// 68.247 us; speedup vs baseline: 24.2766x; 1.2515x over previous
//
#include <hip/hip_runtime.h>

typedef unsigned long long ull;

#define BB 16
#define NN 4096
#define NT 1024
#define EPT 4
#define MAXP 300
#define IOU_THRESH 0.7f
#define SCORE_THR 0.5f

#define FNT 512                 // filter/sort kernel threads
#define FEPT (NN / FNT)         // 8 elements per thread
#define CCAP 1024               // candidate capacity
#define RTOP 512                // fast-path window
#define RW (RTOP / 64)          // 8 mask words per row
#define PD 16                   // scan prefetch depth

__device__ __forceinline__ bool iou_ge(float ix1, float iy1, float ix2, float iy2, float ia,
                                       float x1, float y1, float x2, float y2, float aj) {
    float xx1 = fmaxf(ix1, x1);
    float yy1 = fmaxf(iy1, y1);
    float xx2 = fminf(ix2, x2);
    float yy2 = fminf(iy2, y2);
    float iw = fmaxf(__fsub_rn(xx2, xx1), 0.0f);
    float ih = fmaxf(__fsub_rn(yy2, yy1), 0.0f);
    float inter = __fmul_rn(iw, ih);
    float uni = __fsub_rn(__fadd_rn(ia, aj), inter);
    float iou = __fdiv_rn(inter, uni);
    return iou >= IOU_THRESH;
}

// ============ K1: threshold-filter + compact + sort + SoA emit ============
__global__ __launch_bounds__(FNT, 1) void filter_sort_kernel(const float* __restrict__ proposals,
                                                             const float* __restrict__ cls,
                                                             float* __restrict__ wx1, float* __restrict__ wy1,
                                                             float* __restrict__ wx2, float* __restrict__ wy2,
                                                             float* __restrict__ war,
                                                             unsigned* __restrict__ cidx,
                                                             unsigned* __restrict__ wnv,
                                                             unsigned* __restrict__ need0) {
    __shared__ ull ck[CCAP];                 // 8 KB
    __shared__ unsigned hist[256];
    __shared__ unsigned swsum[FNT / 64];
    __shared__ unsigned s_nv, s_t, s_abv, s_sz;

    const int b = blockIdx.x, tid = threadIdx.x;
    const unsigned lane = tid & 63, wv = tid >> 6;
    const float* Cb = cls + (size_t)b * NN * 2;
    const float4* Pb4 = (const float4*)(proposals + (size_t)b * NN * 4);

    if (tid < 256) hist[tid] = 0;
    ck[tid] = 0; ck[tid + FNT] = 0;
    if (tid == 0) s_nv = 0;
    __syncthreads();

    // ---- pass 1: valid count + level-1 histogram (bin1 = mb>>24, monotone) ----
    unsigned lv = 0;
    #pragma unroll
    for (int c = 0; c < FEPT; ++c) {
        int i = c * FNT + tid;
        float sc = Cb[2 * i + 1];
        if (sc > SCORE_THR) {
            unsigned mb = __float_as_uint(sc) | 0x80000000u;
            atomicAdd(&hist[mb >> 24], 1u);
            ++lv;
        }
    }
    for (int off = 32; off > 0; off >>= 1) lv += __shfl_down(lv, off, 64);
    if (lane == 0) atomicAdd(&s_nv, lv);
    __syncthreads();

    const unsigned nv = s_nv;
    const unsigned target = nv < (unsigned)RTOP ? nv : (unsigned)RTOP;

    // ---- wave 0: suffix-scan over bins, pick t1 ----
    if (tid < 64) {
        unsigned h[4], S[4], local = 0;
        #pragma unroll
        for (int c = 0; c < 4; ++c) { h[c] = hist[tid * 4 + c]; local += h[c]; }
        unsigned inc = local;
        for (int off = 1; off < 64; off <<= 1) {
            unsigned t = __shfl_down(inc, off, 64);
            if (tid + off < 64) inc += t;
        }
        unsigned above = inc - local;
        S[3] = above + h[3];
        S[2] = S[3] + h[2];
        S[1] = S[2] + h[1];
        S[0] = S[1] + h[0];
        int bestc = -1;
        #pragma unroll
        for (int c = 3; c >= 0; --c) if (bestc < 0 && S[c] >= target) bestc = c;
        ull m = __ballot(bestc >= 0);
        int L = 63 - __builtin_clzll(m);
        if (tid == L) {
            s_t = (unsigned)(tid * 4 + bestc);
            s_abv = S[bestc] - h[bestc];
            s_sz = h[bestc];
        }
    }
    __syncthreads();
    const unsigned t1 = s_t;
    const unsigned abv1 = s_abv;
    const int lvl2 = (s_abv + s_sz > CCAP);     // uniform
    unsigned t2 = 0, Ccand;

    if (lvl2) {
        if (tid < 256) hist[tid] = 0;
        __syncthreads();
        #pragma unroll
        for (int c = 0; c < FEPT; ++c) {
            int i = c * FNT + tid;
            float sc = Cb[2 * i + 1];
            if (sc > SCORE_THR) {
                unsigned mb = __float_as_uint(sc) | 0x80000000u;
                if ((mb >> 24) == t1) atomicAdd(&hist[(mb >> 16) & 0xFFu], 1u);
            }
        }
        __syncthreads();
        const unsigned target2 = target - abv1;
        if (tid < 64) {
            unsigned h[4], S[4], local = 0;
            #pragma unroll
            for (int c = 0; c < 4; ++c) { h[c] = hist[tid * 4 + c]; local += h[c]; }
            unsigned inc = local;
            for (int off = 1; off < 64; off <<= 1) {
                unsigned t = __shfl_down(inc, off, 64);
                if (tid + off < 64) inc += t;
            }
            unsigned above = inc - local;
            S[3] = above + h[3];
            S[2] = S[3] + h[2];
            S[1] = S[2] + h[1];
            S[0] = S[1] + h[0];
            int bestc = -1;
            #pragma unroll
            for (int c = 3; c >= 0; --c) if (bestc < 0 && S[c] >= target2) bestc = c;
            ull m = __ballot(bestc >= 0);
            int L = 63 - __builtin_clzll(m);
            if (tid == L) {
                s_t = (unsigned)(tid * 4 + bestc);
                s_abv = S[bestc] - h[bestc];
                s_sz = h[bestc];
            }
        }
        __syncthreads();
        t2 = s_t;
        Ccand = abv1 + s_abv + s_sz;
    } else {
        Ccand = s_abv + s_sz;
    }

    if (tid == 0) { need0[b] = (Ccand > CCAP) ? 1u : 0u; wnv[b] = nv; }

    // ---- compact candidates (superset of exact top-target) ----
    unsigned pf[FEPT];
    ull keys[FEPT];
    unsigned lc = 0;
    #pragma unroll
    for (int c = 0; c < FEPT; ++c) {
        int i = c * FNT + tid;
        float sc = Cb[2 * i + 1];
        unsigned p = 0; ull key = 0;
        if (sc > SCORE_THR) {
            unsigned mb = __float_as_uint(sc) | 0x80000000u;
            unsigned b1 = mb >> 24;
            if (b1 > t1 || (b1 == t1 && (!lvl2 || ((mb >> 16) & 0xFFu) >= t2))) {
                p = 1;
                key = ((ull)mb << 32) | (unsigned)(~i);
            }
        }
        pf[c] = p; keys[c] = key; lc += p;
    }
    unsigned inc = lc;
    for (int off = 1; off < 64; off <<= 1) {
        unsigned o = __shfl_up(inc, off, 64);
        if (lane >= (unsigned)off) inc += o;
    }
    if (lane == 63) swsum[wv] = inc;
    __syncthreads();
    if (tid == 0) {
        unsigned run = 0;
        for (int w = 0; w < FNT / 64; ++w) { unsigned t = swsum[w]; swsum[w] = run; run += t; }
    }
    __syncthreads();
    unsigned pos = swsum[wv] + (inc - lc);
    #pragma unroll
    for (int c = 0; c < FEPT; ++c) {
        if (pf[c]) {
            if (pos < CCAP) ck[pos] = keys[c];
            ++pos;
        }
    }
    __syncthreads();

    // ---- bitonic sort of CCAP keys (descending), pair-enumerated ----
    for (unsigned k = 2; k <= CCAP; k <<= 1) {
        for (unsigned j = k >> 1; j > 0; j >>= 1) {
            unsigned p = tid;                     // exactly CCAP/2 pairs = FNT threads
            unsigned low = p & (j - 1);
            unsigned i2 = ((p ^ low) << 1) | low;
            unsigned ixj = i2 | j;
            ull a = ck[i2], c2 = ck[ixj];
            if ((a < c2) == ((i2 & k) == 0)) { ck[i2] = c2; ck[ixj] = a; }
            __syncthreads();
        }
    }

    // ---- emit sorted top-512: SoA boxes + area + original index ----
    if (tid < RTOP) {
        const size_t base = (size_t)b * RTOP;
        ull key = ck[tid];
        unsigned oi = key ? ~(unsigned)key : 0u;
        float4 v = make_float4(0.f, 0.f, 0.f, 0.f);
        if (key) v = Pb4[oi];
        wx1[base + tid] = v.x; wy1[base + tid] = v.y;
        wx2[base + tid] = v.z; wy2[base + tid] = v.w;
        war[base + tid] = __fmul_rn(__fsub_rn(v.z, v.x), __fsub_rn(v.w, v.y));
        cidx[base + tid] = oi;
    }
}

// ============ K2: 512x512 suppression bit-matrix -> global (parallel) ============
__global__ __launch_bounds__(256) void mask512_kernel(const float* __restrict__ wx1, const float* __restrict__ wy1,
                                                      const float* __restrict__ wx2, const float* __restrict__ wy2,
                                                      const float* __restrict__ war,
                                                      const unsigned* __restrict__ wnv,
                                                      ull* __restrict__ m8) {
    __shared__ float sx1[RTOP], sy1[RTOP], sx2[RTOP], sy2[RTOP], sar[RTOP];  // 10 KB
    const int img = blockIdx.y;
    const unsigned nv = wnv[img];
    const unsigned R2 = nv < (unsigned)RTOP ? nv : (unsigned)RTOP;
    if (R2 == 0) return;
    const int tid = threadIdx.x;
    const size_t base = (size_t)img * RTOP;

    for (int idx = tid; idx < RTOP; idx += 256) {
        sx1[idx] = wx1[base + idx];
        sy1[idx] = wy1[base + idx];
        sx2[idx] = wx2[base + idx];
        sy2[idx] = wy2[base + idx];
        sar[idx] = war[base + idx];
    }
    __syncthreads();

    const unsigned lane = tid & 63;
    const unsigned wvimg = blockIdx.x * 4 + (tid >> 6);   // 0..31 per image
    const unsigned wlastR = (R2 - 1) >> 6;
    ull* mimg = m8 + base * RW;

    for (unsigned i = wvimg; i < R2; i += 32) {           // interleaved: balances triangle
        float ix1 = sx1[i], iy1 = sy1[i], ix2 = sx2[i], iy2 = sy2[i], ia = sar[i];
        const unsigned w0 = i >> 6;
        ull my = 0;
        for (unsigned w = w0; w <= wlastR; ++w) {
            unsigned jj = (w << 6) | lane;
            bool pred = (jj > i) && iou_ge(ix1, iy1, ix2, iy2, ia,
                                           sx1[jj], sy1[jj], sx2[jj], sy2[jj], sar[jj]);
            ull bal = __ballot(pred);
            if (lane == w) my = bal;
        }
        if (lane < RW) {
            ull val = (lane >= w0 && lane <= wlastR) ? my : 0ULL;
            mimg[(size_t)i * RW + lane] = val;            // all 8 words defined
        }
    }
}

// ============ K3: serial greedy OR-scan (1 wave, spill-free pipeline) + output ============
#define PREF_GRP(BUF, G)                                                      \
    do {                                                                      \
        unsigned rb_ = (G) * PD;                                              \
        _Pragma("unroll")                                                     \
        for (int k_ = 0; k_ < PD; ++k_) {                                     \
            unsigned r_ = rb_ + (unsigned)k_;                                 \
            if (r_ >= RTOP) r_ = RTOP - 1;                                    \
            (BUF)[k_] = mimg[(size_t)r_ * RW + wsel];                         \
        }                                                                     \
    } while (0)

#define PROC_GRP(BUF, G)                                                      \
    do {                                                                      \
        unsigned ib_ = (G) * PD;                                              \
        _Pragma("unroll")                                                     \
        for (int k_ = 0; k_ < PD; ++k_) {                                     \
            unsigned i_ = ib_ + (unsigned)k_;                                 \
            bool kb_ = (i_ < R2) && (lane == (i_ >> 6)) &&                    \
                       (((sup >> (i_ & 63)) & 1ULL) == 0ULL);                 \
            ull km_ = __ballot(kb_);                                          \
            bool take_ = (km_ != 0ULL) && (cnt < MAXP);   /* wave-uniform */  \
            if (take_) {                                                      \
                if (lane == 0) ssel[cnt] = i_;                                \
                sup |= (BUF)[k_];                                             \
                ++cnt;                                                        \
            }                                                                 \
        }                                                                     \
    } while (0)

__global__ __launch_bounds__(64, 1) void scan_out_kernel(const float* __restrict__ proposals,
                                                         const float* __restrict__ cls,
                                                         const float* __restrict__ wx1, const float* __restrict__ wy1,
                                                         const float* __restrict__ wx2, const float* __restrict__ wy2,
                                                         const unsigned* __restrict__ cidx,
                                                         const unsigned* __restrict__ wnv,
                                                         const unsigned* __restrict__ need0,
                                                         unsigned* __restrict__ need1,
                                                         const ull* __restrict__ m8,
                                                         float* __restrict__ out) {
    __shared__ unsigned ssel[MAXP];
    const int b = blockIdx.x;
    const unsigned lane = threadIdx.x;                    // 0..63, one wave
    const unsigned nv = wnv[b];
    const unsigned R2 = nv < (unsigned)RTOP ? nv : (unsigned)RTOP;
    const size_t base = (size_t)b * RTOP;
    const float* Cb = cls + (size_t)b * NN * 2;
    const float4* Pb4 = (const float4*)(proposals + (size_t)b * NN * 4);

    ull sup;
    {
        unsigned lb = lane << 6;
        if (lane >= RW || lb >= nv) sup = ~0ULL;
        else if (lb + 64 <= nv) sup = 0ULL;
        else sup = (~0ULL) << (nv - lb);
    }

    unsigned cnt = 0;
    if (R2 > 0) {
        const ull* mimg = m8 + base * RW;
        const unsigned wsel = lane & (RW - 1);
        ull bufA[PD], bufB[PD];
        const unsigned ng = (R2 + PD - 1) / PD;

        PREF_GRP(bufA, 0u);
        unsigned g = 0;
        while (g < ng) {
            if (g + 1 < ng) PREF_GRP(bufB, g + 1);
            PROC_GRP(bufA, g);
            ++g;
            if (cnt >= MAXP || g >= ng) break;
            if (g + 1 < ng) PREF_GRP(bufA, g + 1);
            PROC_GRP(bufB, g);
            ++g;
            if (cnt >= MAXP) break;
        }
    }

    if (lane == 0)
        need1[b] = need0[b] | ((cnt < MAXP && nv > (unsigned)RTOP) ? 1u : 0u);

    // ---- output (cnt is wave-uniform; ssel LDS writes ordered within the wave) ----
    for (unsigned t = lane; t < MAXP; t += 64) {
        float x1, y1, x2, y2; unsigned oi;
        if (cnt == 0) {
            oi = NN - 1;
            float4 v = Pb4[oi];
            x1 = v.x; y1 = v.y; x2 = v.z; y2 = v.w;
        } else {
            unsigned p = ssel[t < cnt ? t : cnt - 1];
            oi = cidx[base + p];
            x1 = wx1[base + p]; y1 = wy1[base + p];
            x2 = wx2[base + p]; y2 = wy2[base + p];
        }
        float sc = Cb[2 * oi + 1];
        float* ob = out + ((size_t)b * MAXP + t) * 4;
        ob[0] = x1; ob[1] = y1; ob[2] = x2; ob[3] = y2;
        out[(size_t)BB * MAXP * 4 + (size_t)b * MAXP + t] = sc;
    }
}

// ============ Guarded full fallback (round-2 monolithic, validated) ============
#define CH 64
#define TPC (CH / EPT)
__global__ __launch_bounds__(NT) void nms_fallback(const float* __restrict__ proposals,
                                                   const float* __restrict__ cls,
                                                   const unsigned* __restrict__ need1,
                                                   float* __restrict__ out) {
    __shared__ unsigned long long skeys[NN];
    __shared__ unsigned char ssup[NN];
    __shared__ float cbx1[2][CH], cby1[2][CH], cbx2[2][CH], cby2[2][CH], cbar[2][CH];
    __shared__ unsigned long long skept[2];
    __shared__ unsigned int ssel[MAXP];
    __shared__ unsigned int swsum[NT / 64];
    __shared__ unsigned int s_nvalid;
    __shared__ unsigned int s_nk;

    const int b = blockIdx.x;
    if (need1 && !need1[b]) return;
    const int tid = threadIdx.x;
    const float* Pb = proposals + (size_t)b * NN * 4;
    const float* Cb = cls + (size_t)b * NN * 2;

    if (tid == 0) s_nvalid = 0;
    __syncthreads();

    unsigned lv = 0;
    for (int i = tid; i < NN; i += NT) {
        float sc = Cb[i * 2 + 1];
        bool valid = sc > SCORE_THR;
        unsigned mb = valid ? (__float_as_uint(sc) | 0x80000000u) : 0u;
        skeys[i] = ((unsigned long long)mb << 32) | (unsigned)(~i);
        lv += valid ? 1u : 0u;
    }
    for (int off = 32; off > 0; off >>= 1) lv += __shfl_down(lv, off, 64);
    if ((tid & 63) == 0) atomicAdd(&s_nvalid, lv);

    for (unsigned k = 2; k <= NN; k <<= 1) {
        for (unsigned j = k >> 1; j > 0; j >>= 1) {
            __syncthreads();
            for (unsigned p = tid; p < NN / 2; p += NT) {
                unsigned low = p & (j - 1);
                unsigned i = ((p ^ low) << 1) | low;
                unsigned ixj = i | j;
                unsigned long long a = skeys[i], c = skeys[ixj];
                if ((a < c) == ((i & k) == 0)) { skeys[i] = c; skeys[ixj] = a; }
            }
        }
    }
    __syncthreads();

    const unsigned n_valid = s_nvalid;

    unsigned ordj[EPT];
    float bx1[EPT], by1[EPT], bx2[EPT], by2[EPT], bar[EPT];
    int rflag[EPT];
    for (int c2 = 0; c2 < EPT; ++c2) {
        int j = tid * EPT + c2;
        unsigned oi = ~(unsigned)skeys[j];
        ordj[c2] = oi;
        const float* P = Pb + (size_t)oi * 4;
        float x1 = P[0], y1 = P[1], x2 = P[2], y2 = P[3];
        bx1[c2] = x1; by1[c2] = y1; bx2[c2] = x2; by2[c2] = y2;
        bar[c2] = __fmul_rn(__fsub_rn(x2, x1), __fsub_rn(y2, y1));
        int sup = (j < (int)n_valid) ? 0 : 1;
        rflag[c2] = sup;
        ssup[j] = (unsigned char)sup;
    }

    const unsigned nch = (n_valid + CH - 1) / CH;
    for (unsigned c = 0; c < nch; ++c) {
        const int p = (int)(c & 1);
        if (tid >= (int)(TPC * c) && tid < (int)(TPC * (c + 1))) {
            int bse = (tid - TPC * c) * EPT;
            #pragma unroll
            for (int c2 = 0; c2 < EPT; ++c2) {
                int l = bse + c2;
                cbx1[p][l] = bx1[c2]; cby1[p][l] = by1[c2];
                cbx2[p][l] = bx2[c2]; cby2[p][l] = by2[c2];
                cbar[p][l] = bar[c2];
            }
        }
        __syncthreads();

        if (tid < CH) {
            const int l = tid;
            const int j = (int)(c * CH) + l;
            float x1 = cbx1[p][l], y1 = cby1[p][l], x2 = cbx2[p][l], y2 = cby2[p][l];
            float ar = cbar[p][l];
            int supl = ssup[j];
            unsigned long long row = 0ULL;
            for (int m = l + 1; m < CH; ++m) {
                bool s = iou_ge(x1, y1, x2, y2, ar,
                                cbx1[p][m], cby1[p][m], cbx2[p][m], cby2[p][m], cbar[p][m]);
                if (s) row |= (1ULL << m);
            }
            unsigned long long S = __ballot(supl != 0);
            for (int i = 0; i < CH; ++i) {
                unsigned long long ri = __shfl(row, i, 64);
                if (!((S >> i) & 1ULL)) S |= ri;
            }
            ssup[j] = (unsigned char)((S >> l) & 1ULL);
            if (l == 0) skept[p] = ~S;
        }
        __syncthreads();

        const int myFirst = tid * EPT;
        if (myFirst >= (int)(CH * (c + 1)) &&
            !(rflag[0] & rflag[1] & rflag[2] & rflag[3])) {
            unsigned long long K = skept[p];
            while (K) {
                int m = __builtin_ctzll(K);
                K &= K - 1;
                float mx1 = cbx1[p][m], my1 = cby1[p][m];
                float mx2 = cbx2[p][m], my2 = cby2[p][m];
                float ma = cbar[p][m];
                #pragma unroll
                for (int c2 = 0; c2 < EPT; ++c2) {
                    if (!rflag[c2]) {
                        bool s = iou_ge(mx1, my1, mx2, my2, ma,
                                        bx1[c2], by1[c2], bx2[c2], by2[c2], bar[c2]);
                        if (s) { rflag[c2] = 1; ssup[myFirst + c2] = 1; }
                    }
                }
            }
        }
    }
    __syncthreads();

    unsigned kflag[EPT];
    unsigned lc = 0;
    for (int c2 = 0; c2 < EPT; ++c2) {
        int j = tid * EPT + c2;
        kflag[c2] = ssup[j] ? 0u : 1u;
        lc += kflag[c2];
    }
    unsigned lane = tid & 63, wid = tid >> 6;
    unsigned inc = lc;
    for (int off = 1; off < 64; off <<= 1) {
        unsigned o = __shfl_up(inc, off, 64);
        if (lane >= (unsigned)off) inc += o;
    }
    if (lane == 63) swsum[wid] = inc;
    __syncthreads();
    if (tid == 0) {
        unsigned run = 0;
        for (int w = 0; w < NT / 64; ++w) { unsigned t = swsum[w]; swsum[w] = run; run += t; }
        s_nk = run;
    }
    __syncthreads();
    unsigned bse = swsum[wid] + (inc - lc);
    for (int c2 = 0; c2 < EPT; ++c2) {
        if (kflag[c2]) {
            if (bse < MAXP) ssel[bse] = ordj[c2];
            ++bse;
        }
    }
    const unsigned nk_pre = s_nk;
    __syncthreads();

    if (tid < MAXP) {
        if (nk_pre == 0) {
            ssel[tid] = ~(unsigned)skeys[NN - 1];
        } else if (tid >= nk_pre) {
            ssel[tid] = ssel[nk_pre - 1];
        }
    }
    __syncthreads();

    if (tid < MAXP) {
        unsigned si = ssel[tid];
        const float* P = Pb + (size_t)si * 4;
        float* ob = out + ((size_t)b * MAXP + tid) * 4;
        ob[0] = P[0]; ob[1] = P[1]; ob[2] = P[2]; ob[3] = P[3];
        out[(size_t)BB * MAXP * 4 + (size_t)b * MAXP + tid] = Cb[si * 2 + 1];
    }
}

extern "C" void kernel_launch(void* const* d_in, const int* in_sizes, int n_in,
                              void* d_out, int out_size, void* d_ws, size_t ws_size,
                              hipStream_t stream) {
    const float* proposals = (const float*)d_in[0];
    const float* cls = (const float*)d_in[1];
    float* out = (float*)d_out;

    const size_t S = (size_t)BB * RTOP;
    const size_t need_sz = S * RW * sizeof(ull)       // m8
                         + S * 5 * sizeof(float)      // SoA
                         + S * sizeof(unsigned)       // cidx
                         + 3 * BB * sizeof(unsigned) + 256;
    if (ws_size < need_sz) {
        nms_fallback<<<BB, NT, 0, stream>>>(proposals, cls, (const unsigned*)nullptr, out);
        return;
    }

    ull* m8 = (ull*)d_ws;                             // 512 KB
    float* wx1 = (float*)(m8 + S * RW);
    float* wy1 = wx1 + S;
    float* wx2 = wy1 + S;
    float* wy2 = wx2 + S;
    float* war = wy2 + S;
    unsigned* cidx = (unsigned*)(war + S);
    unsigned* wnv = cidx + S;
    unsigned* need0 = wnv + BB;
    unsigned* need1 = need0 + BB;

    filter_sort_kernel<<<BB, FNT, 0, stream>>>(proposals, cls, wx1, wy1, wx2, wy2, war,
                                               cidx, wnv, need0);
    mask512_kernel<<<dim3(RTOP / 64, BB), 256, 0, stream>>>(wx1, wy1, wx2, wy2, war, wnv, m8);
    scan_out_kernel<<<BB, 64, 0, stream>>>(proposals, cls, wx1, wy1, wx2, wy2,
                                           cidx, wnv, need0, need1, m8, out);
    nms_fallback<<<BB, NT, 0, stream>>>(proposals, cls, need1, out);   // no-op unless flagged
}